// Round 17
// baseline (248.906 us; speedup 1.0000x reference)
//
#include <hip/hip_runtime.h>
#include <hip/hip_bf16.h>

// Hopfield forward, blocked factored Gauss-Seidel.
// Round 17 = r14 base + SPECULATIVE ballot chain: at each step compute both
// candidate v's AND both candidate ballot words before the step's sign bit is
// known; resolve via scalar s_cselect. Overlaps consecutive cross-lane
// round-trips (the measured ~47cy/step cost). Bit-exact vs r14:
// v-K == v+(K^signbit); ballot on identical post-update values; same order.

#define OFF_COLB   0u                       // u64 [8][4096]  colbitsP
#define OFF_XBITS  (256u<<10)               // u64 [512][64]  row bits
#define OFF_XBW    (512u<<10)               // u64 [64][512]  xbitsW
#define OFF_KF     (768u<<10)               // f32 [64][64][64] Kdiag : 1 MB
#define OFF_BCORR  (1792u<<10)              // f32 [4096] baseCorr
#define OFF_U      (1808u<<10)              // f32 [64][512] U
#define OFF_CST    (1936u<<10)              // float4 [4096]
#define OFF_P0     (2000u<<10)              // f32 [512]
#define OFF_SBITS  (2002u<<10)              // u64 [64]
#define OFF_CNT    (2003u<<10)              // int [4096]
#define OFF_HDR    (2019u<<10)              // f32 [16]
#define OFF_BS0    (2020u<<10)              // f32 [64]
#define OFF_BS0C   (2021u<<10)              // f32 [64]

template<int CTRL, int RMASK>
__device__ __forceinline__ float dpp_add(float x){
  int t = __builtin_amdgcn_update_dpp(0, __float_as_int(x), CTRL, RMASK, 0xf, true);
  return x + __int_as_float(t);
}
__device__ __forceinline__ float wave_allsum(float x){
  x = dpp_add<0x111,0xf>(x);
  x = dpp_add<0x112,0xf>(x);
  x = dpp_add<0x114,0xf>(x);
  x = dpp_add<0x118,0xf>(x);
  x = dpp_add<0x142,0xa>(x);
  x = dpp_add<0x143,0xc>(x);
  return __int_as_float(__builtin_amdgcn_readlane(__float_as_int(x), 63));
}

// ---- row bits + transposed-block layout
__global__ void k_xbits(const float* __restrict__ llv, unsigned long long* __restrict__ xbits,
                        unsigned long long* __restrict__ xbitsW){
  int w = threadIdx.x >> 6, lane = threadIdx.x & 63;
  int l = blockIdx.x*4 + w;
  unsigned long long myword = 0;
  for (int c = 0; c < 64; ++c){
    float v = llv[(size_t)l*4096 + c*64 + lane];
    unsigned long long b = __ballot(v >= 0.0f);
    if (c == lane) myword = b;
  }
  xbits[(size_t)l*64 + lane] = myword;
  xbitsW[(size_t)lane*512 + l] = myword;
}

// ---- bit transpose
__global__ void k_bitT(const unsigned long long* __restrict__ xbits,
                       unsigned long long* __restrict__ colbitsP){
  int li = blockIdx.x, ii = blockIdx.y, lane = threadIdx.x;
  unsigned long long w = xbits[(size_t)(li*64 + lane)*64 + ii];
  unsigned long long myw = 0;
  for (int j = 0; j < 64; ++j){
    unsigned long long b = __ballot((w >> j) & 1ull);
    if (j == lane) myw = b;
  }
  colbitsP[(size_t)li*4096 + ii*64 + lane] = myw;
}

// ---- column positive counts
__global__ void k_colc(const unsigned long long* __restrict__ colbitsP, int* __restrict__ colcnt){
  int i = blockIdx.x*256 + threadIdx.x;
  int c = 0;
  #pragma unroll
  for (int wl = 0; wl < 8; ++wl) c += __popcll(colbitsP[(size_t)wl*4096 + i]);
  colcnt[i] = c;
}

// ---- rho
__global__ void k_rho(const int* __restrict__ colcnt, float* __restrict__ hdr){
  __shared__ int sh[256];
  int tid = threadIdx.x;
  int s = 0;
  for (int k = tid; k < 4096; k += 256) s += colcnt[k];
  sh[tid] = s; __syncthreads();
  for (int st = 128; st > 0; st >>= 1){
    if (tid < st) sh[tid] += sh[tid + st];
    __syncthreads();
  }
  if (tid == 0){
    int num = 2*sh[0] - 2097152;
    hdr[0] = (float)num * (1.0f/2097152.0f);
  }
}

// ---- per-step constants
__global__ void k_const(const int* __restrict__ colcnt, const float* __restrict__ hdr,
                        const float* __restrict__ s0, float4* __restrict__ cst){
  int i = blockIdx.x*256 + threadIdx.x;
  float rho = hdr[0];
  float c  = (float)(2*colcnt[i] - 512);
  float r2 = rho*rho;
  float q  = 512.0f + 512.0f*r2 - 2.0f*rho*c;
  float s  = s0[i];
  float4 o;
  o.x = q * s;
  o.y = rho*c - 512.0f*r2;
  o.z = 1.0f - s;
  o.w = c;
  cst[i] = o;
}

// ---- diagonal K blocks + baseCorr + block s0 sums
__global__ void k_kdiag(const unsigned long long* __restrict__ colbitsP,
                        const float4* __restrict__ cst, const float* __restrict__ s0,
                        const float* __restrict__ hdr,
                        float* __restrict__ Kf, float* __restrict__ baseCorr,
                        float* __restrict__ blkS0, float* __restrict__ blkS0C){
  __shared__ unsigned long long cb[8][64];
  __shared__ float Kl[64][64];
  __shared__ float cs[64], ss[64];
  int b = blockIdx.x, i0 = b*64, tid = threadIdx.x;  // 256 threads
  for (int k = tid; k < 512; k += 256)
    cb[k>>6][k&63] = colbitsP[(size_t)(k>>6)*4096 + i0 + (k&63)];
  if (tid < 64){ cs[tid] = cst[i0+tid].w; ss[tid] = s0[i0+tid]; }
  __syncthreads();
  float rho = hdr[0];
  float r2t = 512.0f*rho*rho;
  #pragma unroll
  for (int k = 0; k < 16; ++k){
    int q = tid*16 + k;
    int t = q >> 6, j = q & 63;
    int acc = 0;
    #pragma unroll
    for (int wl = 0; wl < 8; ++wl) acc += __popcll(cb[wl][t] ^ cb[wl][j]);
    float G = (float)(512 - 2*acc);
    float kf = G - rho*(cs[t]+cs[j]) + r2t;
    Kl[t][j] = kf;
    Kf[(size_t)b*4096 + q] = kf;
  }
  __syncthreads();
  if (tid < 64){
    float bc = 0.0f;
    for (int j = 0; j < tid; ++j) bc = fmaf(ss[j], Kl[tid][j], bc);
    baseCorr[i0 + tid] = bc;
  }
  if (tid == 64){
    float a = 0.0f, b2 = 0.0f;
    for (int j = 0; j < 64; ++j){ a += ss[j]; b2 = fmaf(ss[j], cs[j], b2); }
    blkS0[b] = a; blkS0C[b] = b2;
  }
}

// ---- U[b][l]
__global__ void k_u(const unsigned long long* __restrict__ xbits, const float* __restrict__ s0,
                    float* __restrict__ U){
  __shared__ float s0l[64];
  int b = blockIdx.x, l = threadIdx.x;  // 512 threads
  if (l < 64) s0l[l] = s0[b*64 + l];
  __syncthreads();
  unsigned long long w = xbits[(size_t)l*64 + b];
  unsigned int lo = (unsigned)w, hi = (unsigned)(w >> 32);
  unsigned int nlo = ~lo, nhi = ~hi;
  float acc = 0.0f;
  #pragma unroll
  for (int j = 0; j < 32; ++j){
    unsigned int m = (nlo << (31-j)) & 0x80000000u;
    acc += __uint_as_float(__float_as_uint(s0l[j]) ^ m);
  }
  #pragma unroll
  for (int j = 0; j < 32; ++j){
    unsigned int m = (nhi << (31-j)) & 0x80000000u;
    acc += __uint_as_float(__float_as_uint(s0l[32+j]) ^ m);
  }
  U[(size_t)b*512 + l] = acc;
}

// ---- p0
__global__ void k_pinit(const float* __restrict__ llv, const float* __restrict__ s0,
                        float* __restrict__ p0){
  int l = blockIdx.x, lane = threadIdx.x;
  float acc = 0.0f;
  for (int c = 0; c < 64; ++c){
    float v = llv[(size_t)l*4096 + c*64 + lane];
    float sg = (v >= 0.0f) ? 1.0f : -1.0f;
    acc = fmaf(sg, s0[c*64 + lane], acc);
  }
  float tot = wave_allsum(acc);
  if (lane == 0) p0[l] = tot;
}

// ---- phase-1 accumulate helper (r14 verbatim)
#define ACC1(F, W, JS) { \
  unsigned int m_ = ((~(W)) << (31-(JS))) & 0x80000000u; \
  acc += __uint_as_float(__float_as_uint(F) ^ m_); }

// ---- speculative ballot chain step. neg_ holds the ballot word valid for
// step J (signs of v after updates 0..J-1). Both next-word candidates are
// computed BEFORE bit J is consumed; resolve is scalar s_cselect.
#define BSTP(KVAL, J) { \
  unsigned bj_ = (unsigned)(neg_ >> (J)) & 1u; \
  sg_ |= ((unsigned long long)(bj_ ^ 1u)) << (J); \
  float vP_ = v + (KVAL); \
  float vM_ = v - (KVAL); \
  unsigned long long nP_ = __ballot(__float_as_int(vP_) < 0); \
  unsigned long long nM_ = __ballot(__float_as_int(vM_) < 0); \
  v    = bj_ ? vM_ : vP_; \
  neg_ = bj_ ? nM_ : nP_; }
#define BST4(Q, J0) BSTP(Q.x,(J0)+0) BSTP(Q.y,(J0)+1) BSTP(Q.z,(J0)+2) BSTP(Q.w,(J0)+3)

// ---- the sweep: LDS-resident + T14 async-stage + speculative ballot chain
__global__ __launch_bounds__(512, 1)
void k_sweep6(const unsigned long long* __restrict__ colbitsP,
              const unsigned long long* __restrict__ xbitsW,
              const float* __restrict__ Kf, const float* __restrict__ baseCorr,
              const float* __restrict__ blkS0, const float* __restrict__ blkS0C,
              const float* __restrict__ U, const float4* __restrict__ cst,
              const float* __restrict__ p0, const float* __restrict__ s0,
              const float* __restrict__ hdr, unsigned long long* __restrict__ sbits)
{
  __shared__ float Kl[2][64][64];                 // 32 KB, f4-swizzled rows
  __shared__ unsigned long long cbl[2][8][64];    // 8 KB
  __shared__ unsigned long long xbl[2][512];      // 8 KB
  __shared__ float Ul[2][512];                    // 4 KB
  __shared__ float4 cstl[2][64];                  // 2 KB
  __shared__ float bcl[2][64];                    // 0.5 KB
  __shared__ float bs0l[64], bscl[64];            // 0.5 KB
  __shared__ float p[512];
  __shared__ float part[8][64];
  __shared__ float red[512];
  __shared__ unsigned long long sig;

  int tid = threadIdx.x, g = tid >> 6, t = tid & 63;
  float rho = hdr[0];

  // prologue: p, P, T + per-block scalars
  p[tid] = p0[tid];
  red[tid] = p0[tid];
  if (tid < 64){ bs0l[tid] = blkS0[tid]; bscl[tid] = blkS0C[tid]; }
  __syncthreads();
  for (int st = 256; st > 0; st >>= 1){ if (tid < st) red[tid] += red[tid+st]; __syncthreads(); }
  float Preg = red[0];
  __syncthreads();
  { float a = 0.0f; for (int k = 0; k < 8; ++k) a += s0[tid*8 + k]; red[tid] = a; }
  __syncthreads();
  for (int st = 256; st > 0; st >>= 1){ if (tid < st) red[tid] += red[tid+st]; __syncthreads(); }
  float Treg = red[0];
  __syncthreads();

  // ---- stage group 0 directly ----
  {
    const float4* Ks = (const float4*)(Kf);
    #pragma unroll
    for (int k = 0; k < 4; ++k){
      int e = tid + k*512;
      float4 vv = Ks[e];
      int gie = e >> 10, row = (e >> 4) & 63, f = e & 15;
      *((float4*)&Kl[gie][row][0] + (f ^ (row & 15))) = vv;
    }
    #pragma unroll
    for (int k = 0; k < 2; ++k){
      int e = tid + k*512;
      int run = e >> 6, tt = e & 63, gie = run >> 3, wl = run & 7;
      cbl[gie][wl][tt] = colbitsP[(size_t)wl*4096 + gie*64 + tt];
    }
    #pragma unroll
    for (int k = 0; k < 2; ++k){
      int e = tid + k*512;
      ((unsigned long long*)xbl)[e] = xbitsW[e];
    }
    #pragma unroll
    for (int k = 0; k < 2; ++k){
      int e = tid + k*512;
      ((float*)Ul)[e] = U[e];
    }
    if (tid < 128){
      ((float4*)cstl)[tid] = cst[tid];
      ((float*)bcl)[tid]   = baseCorr[tid];
    }
  }
  __syncthreads();

  for (int grp = 0; grp < 32; ++grp){
    int ng = grp + 1;
    bool pf = (ng < 32);
    // ---- T14 issue-early: next group's loads into registers ----
    float4 kv0, kv1, kv2, kv3, cstv;
    unsigned long long cbv0, cbv1, xbv0, xbv1;
    float uv0, uv1, bcv;
    if (pf){
      const float4* Ks = (const float4*)(Kf + (size_t)ng*8192);
      kv0 = Ks[tid]; kv1 = Ks[tid+512]; kv2 = Ks[tid+1024]; kv3 = Ks[tid+1536];
      { int e = tid;       int run = e>>6, tt = e&63;
        cbv0 = colbitsP[(size_t)(run&7)*4096 + (ng*2 + (run>>3))*64 + tt]; }
      { int e = tid + 512; int run = e>>6, tt = e&63;
        cbv1 = colbitsP[(size_t)(run&7)*4096 + (ng*2 + (run>>3))*64 + tt]; }
      xbv0 = xbitsW[(size_t)ng*1024 + tid]; xbv1 = xbitsW[(size_t)ng*1024 + tid + 512];
      uv0  = U[(size_t)ng*1024 + tid];      uv1  = U[(size_t)ng*1024 + tid + 512];
      if (tid < 128){ cstv = cst[ng*128 + tid]; bcv = baseCorr[ng*128 + tid]; }
    }

    #pragma unroll
    for (int gi = 0; gi < 2; ++gi){
      int b = grp*2 + gi;
      // ---- phase 1 (r14 verbatim) ----
      {
        unsigned long long w = cbl[gi][g][t];
        unsigned int lo = (unsigned)w, hi = (unsigned)(w >> 32);
        const float4* pw = (const float4*)(p + g*64);
        float acc = 0.0f;
        #pragma unroll
        for (int f = 0; f < 16; ++f){
          float4 q = pw[f];
          if (f < 8){
            ACC1(q.x, lo, 4*f+0) ACC1(q.y, lo, 4*f+1)
            ACC1(q.z, lo, 4*f+2) ACC1(q.w, lo, 4*f+3)
          } else {
            ACC1(q.x, hi, 4*f-32) ACC1(q.y, hi, 4*f-31)
            ACC1(q.z, hi, 4*f-30) ACC1(q.w, hi, 4*f-29)
          }
        }
        part[g][t] = acc;
      }
      __syncthreads();                             // B1

      if (g == 0){
        const float4* Kp = (const float4*)&Kl[gi][t][0];
        int sw = t & 15;
        float S = 0.0f;
        #pragma unroll
        for (int gg = 0; gg < 8; ++gg) S += part[gg][t];
        float4 cc = cstl[gi][t];
        float bc_ = bcl[gi][t];
        float v = S - cc.x - rho*Preg - cc.y*Treg - bc_;
        float4 C0 = Kp[0^sw], C1 = Kp[1^sw], C2 = Kp[2^sw];
        unsigned long long sg_ = 0ull;
        unsigned long long neg_ = __ballot(__float_as_int(v) < 0);  // signs of base v
        BST4(C0, 0);   C0 = Kp[3^sw];
        BST4(C1, 4);   C1 = Kp[4^sw];
        BST4(C2, 8);   C2 = Kp[5^sw];
        BST4(C0, 12);  C0 = Kp[6^sw];
        BST4(C1, 16);  C1 = Kp[7^sw];
        BST4(C2, 20);  C2 = Kp[8^sw];
        BST4(C0, 24);  C0 = Kp[9^sw];
        BST4(C1, 28);  C1 = Kp[10^sw];
        BST4(C2, 32);  C2 = Kp[11^sw];
        BST4(C0, 36);  C0 = Kp[12^sw];
        BST4(C1, 40);  C1 = Kp[13^sw];
        BST4(C2, 44);  C2 = Kp[14^sw];
        BST4(C0, 48);  C0 = Kp[15^sw];
        BST4(C1, 52);
        BST4(C2, 56);
        BST4(C0, 60);
        if (t == 0){ sig = sg_; sbits[b] = sg_; }
        float sv = ((sg_ >> t) & 1ull) ? cc.w : -cc.w;
        float sc = wave_allsum(sv);
        int pcs = __popcll(sg_);
        Preg += sc - bscl[b];
        Treg += (float)(2*pcs - 64) - bs0l[b];
      }
      __syncthreads();                             // B2
      // ---- phase 3 (no B3: p wave-local; part/sig guarded by B1/B2) ----
      {
        unsigned long long sgv = sig;
        int pc = __popcll(xbl[gi][tid] ^ sgv);
        p[tid] = p[tid] + (float)(64 - 2*pc) - Ul[gi][tid];
      }
    }

    // ---- T14 write-late: prefetched registers -> LDS, then group barrier ----
    if (pf){
      { int e = tid;        int gie=e>>10, row=(e>>4)&63, f=e&15;
        *((float4*)&Kl[gie][row][0] + (f ^ (row & 15))) = kv0; }
      { int e = tid + 512;  int gie=e>>10, row=(e>>4)&63, f=e&15;
        *((float4*)&Kl[gie][row][0] + (f ^ (row & 15))) = kv1; }
      { int e = tid + 1024; int gie=e>>10, row=(e>>4)&63, f=e&15;
        *((float4*)&Kl[gie][row][0] + (f ^ (row & 15))) = kv2; }
      { int e = tid + 1536; int gie=e>>10, row=(e>>4)&63, f=e&15;
        *((float4*)&Kl[gie][row][0] + (f ^ (row & 15))) = kv3; }
      { int e = tid;       int run=e>>6, tt=e&63; cbl[run>>3][run&7][tt] = cbv0; }
      { int e = tid + 512; int run=e>>6, tt=e&63; cbl[run>>3][run&7][tt] = cbv1; }
      ((unsigned long long*)xbl)[tid]       = xbv0;
      ((unsigned long long*)xbl)[tid + 512] = xbv1;
      ((float*)Ul)[tid]       = uv0;
      ((float*)Ul)[tid + 512] = uv1;
      if (tid < 128){ ((float4*)cstl)[tid] = cstv; ((float*)bcl)[tid] = bcv; }
    }
    __syncthreads();                               // B4 (group boundary)
  }
}

// ---- exact integer scores + argmax one-hot
__global__ void k_scores(const unsigned long long* __restrict__ xbits,
                         const unsigned long long* __restrict__ sbits,
                         float* __restrict__ out){
  __shared__ unsigned long long sb[64];
  __shared__ int bestkey;
  int tid = threadIdx.x;  // 512
  if (tid < 64) sb[tid] = sbits[tid];
  if (tid == 0) bestkey = -1;
  __syncthreads();
  int acc = 0;
  #pragma unroll
  for (int w = 0; w < 64; ++w)
    acc += __popcll(xbits[(size_t)tid*64 + w] ^ sb[w]);
  int dot = 4096 - 2*acc;
  int ad  = dot < 0 ? -dot : dot;
  int key = (ad << 10) | (511 - tid);
  atomicMax(&bestkey, key);
  __syncthreads();
  int bl = 511 - (bestkey & 1023);
  float val = (float)(bestkey >> 10) * (1.0f/4096.0f);
  out[tid] = (tid == bl) ? val : 0.0f;
}

extern "C" void kernel_launch(void* const* d_in, const int* in_sizes, int n_in,
                              void* d_out, int out_size, void* d_ws, size_t ws_size,
                              hipStream_t stream){
  const float* s0  = (const float*)d_in[0];   // [4096]
  const float* llv = (const float*)d_in[1];   // [512][4096]
  float* out = (float*)d_out;                 // [512]
  char* ws = (char*)d_ws;

  unsigned long long* colbitsP = (unsigned long long*)(ws + OFF_COLB);
  unsigned long long* xbits    = (unsigned long long*)(ws + OFF_XBITS);
  unsigned long long* xbitsW   = (unsigned long long*)(ws + OFF_XBW);
  float*  Kf    = (float*)(ws + OFF_KF);
  float*  bcorr = (float*)(ws + OFF_BCORR);
  float*  U     = (float*)(ws + OFF_U);
  float4* cst   = (float4*)(ws + OFF_CST);
  float*  p0    = (float*)(ws + OFF_P0);
  unsigned long long* sbits = (unsigned long long*)(ws + OFF_SBITS);
  int*    colcnt = (int*)(ws + OFF_CNT);
  float*  hdr   = (float*)(ws + OFF_HDR);
  float*  bS0   = (float*)(ws + OFF_BS0);
  float*  bS0C  = (float*)(ws + OFF_BS0C);

  k_xbits<<<128, 256, 0, stream>>>(llv, xbits, xbitsW);
  k_bitT<<<dim3(8, 64), 64, 0, stream>>>(xbits, colbitsP);
  k_colc<<<16, 256, 0, stream>>>(colbitsP, colcnt);
  k_rho<<<1, 256, 0, stream>>>(colcnt, hdr);
  k_const<<<16, 256, 0, stream>>>(colcnt, hdr, s0, cst);
  k_kdiag<<<64, 256, 0, stream>>>(colbitsP, cst, s0, hdr, Kf, bcorr, bS0, bS0C);
  k_u<<<64, 512, 0, stream>>>(xbits, s0, U);
  k_pinit<<<512, 64, 0, stream>>>(llv, s0, p0);
  k_sweep6<<<1, 512, 0, stream>>>(colbitsP, xbitsW, Kf, bcorr, bS0, bS0C, U, cst, p0, s0, hdr, sbits);
  k_scores<<<1, 512, 0, stream>>>(xbits, sbits, out);
}

// Round 18
// 222.373 us; speedup vs baseline: 1.1193x; 1.1193x over previous
//
#include <hip/hip_runtime.h>
#include <hip/hip_bf16.h>

// Hopfield forward, blocked factored Gauss-Seidel.
// Round 18 = r14 chain (best: one ballot/step) + two non-chain cuts:
//  (1) redundant chain in ALL 8 waves (identical inputs -> identical sg_):
//      B2 and sig publication removed; part[] double-buffered by parity;
//      one barrier per block + Bpre/B4 at group boundary.
//  (2) 4-accumulator phase-1 (r15-proven): 4 independent LDS/add streams.

#define OFF_COLB   0u                       // u64 [8][4096]  colbitsP
#define OFF_XBITS  (256u<<10)               // u64 [512][64]  row bits
#define OFF_XBW    (512u<<10)               // u64 [64][512]  xbitsW
#define OFF_KF     (768u<<10)               // f32 [64][64][64] Kdiag : 1 MB
#define OFF_BCORR  (1792u<<10)              // f32 [4096] baseCorr
#define OFF_U      (1808u<<10)              // f32 [64][512] U
#define OFF_CST    (1936u<<10)              // float4 [4096]
#define OFF_P0     (2000u<<10)              // f32 [512]
#define OFF_SBITS  (2002u<<10)              // u64 [64]
#define OFF_CNT    (2003u<<10)              // int [4096]
#define OFF_HDR    (2019u<<10)              // f32 [16]
#define OFF_BS0    (2020u<<10)              // f32 [64]
#define OFF_BS0C   (2021u<<10)              // f32 [64]

template<int CTRL, int RMASK>
__device__ __forceinline__ float dpp_add(float x){
  int t = __builtin_amdgcn_update_dpp(0, __float_as_int(x), CTRL, RMASK, 0xf, true);
  return x + __int_as_float(t);
}
__device__ __forceinline__ float wave_allsum(float x){
  x = dpp_add<0x111,0xf>(x);
  x = dpp_add<0x112,0xf>(x);
  x = dpp_add<0x114,0xf>(x);
  x = dpp_add<0x118,0xf>(x);
  x = dpp_add<0x142,0xa>(x);
  x = dpp_add<0x143,0xc>(x);
  return __int_as_float(__builtin_amdgcn_readlane(__float_as_int(x), 63));
}

// ---- row bits + transposed-block layout
__global__ void k_xbits(const float* __restrict__ llv, unsigned long long* __restrict__ xbits,
                        unsigned long long* __restrict__ xbitsW){
  int w = threadIdx.x >> 6, lane = threadIdx.x & 63;
  int l = blockIdx.x*4 + w;
  unsigned long long myword = 0;
  for (int c = 0; c < 64; ++c){
    float v = llv[(size_t)l*4096 + c*64 + lane];
    unsigned long long b = __ballot(v >= 0.0f);
    if (c == lane) myword = b;
  }
  xbits[(size_t)l*64 + lane] = myword;
  xbitsW[(size_t)lane*512 + l] = myword;
}

// ---- bit transpose
__global__ void k_bitT(const unsigned long long* __restrict__ xbits,
                       unsigned long long* __restrict__ colbitsP){
  int li = blockIdx.x, ii = blockIdx.y, lane = threadIdx.x;
  unsigned long long w = xbits[(size_t)(li*64 + lane)*64 + ii];
  unsigned long long myw = 0;
  for (int j = 0; j < 64; ++j){
    unsigned long long b = __ballot((w >> j) & 1ull);
    if (j == lane) myw = b;
  }
  colbitsP[(size_t)li*4096 + ii*64 + lane] = myw;
}

// ---- column positive counts
__global__ void k_colc(const unsigned long long* __restrict__ colbitsP, int* __restrict__ colcnt){
  int i = blockIdx.x*256 + threadIdx.x;
  int c = 0;
  #pragma unroll
  for (int wl = 0; wl < 8; ++wl) c += __popcll(colbitsP[(size_t)wl*4096 + i]);
  colcnt[i] = c;
}

// ---- rho
__global__ void k_rho(const int* __restrict__ colcnt, float* __restrict__ hdr){
  __shared__ int sh[256];
  int tid = threadIdx.x;
  int s = 0;
  for (int k = tid; k < 4096; k += 256) s += colcnt[k];
  sh[tid] = s; __syncthreads();
  for (int st = 128; st > 0; st >>= 1){
    if (tid < st) sh[tid] += sh[tid + st];
    __syncthreads();
  }
  if (tid == 0){
    int num = 2*sh[0] - 2097152;
    hdr[0] = (float)num * (1.0f/2097152.0f);
  }
}

// ---- per-step constants
__global__ void k_const(const int* __restrict__ colcnt, const float* __restrict__ hdr,
                        const float* __restrict__ s0, float4* __restrict__ cst){
  int i = blockIdx.x*256 + threadIdx.x;
  float rho = hdr[0];
  float c  = (float)(2*colcnt[i] - 512);
  float r2 = rho*rho;
  float q  = 512.0f + 512.0f*r2 - 2.0f*rho*c;
  float s  = s0[i];
  float4 o;
  o.x = q * s;
  o.y = rho*c - 512.0f*r2;
  o.z = 1.0f - s;
  o.w = c;
  cst[i] = o;
}

// ---- diagonal K blocks + baseCorr + block s0 sums
__global__ void k_kdiag(const unsigned long long* __restrict__ colbitsP,
                        const float4* __restrict__ cst, const float* __restrict__ s0,
                        const float* __restrict__ hdr,
                        float* __restrict__ Kf, float* __restrict__ baseCorr,
                        float* __restrict__ blkS0, float* __restrict__ blkS0C){
  __shared__ unsigned long long cb[8][64];
  __shared__ float Kl[64][64];
  __shared__ float cs[64], ss[64];
  int b = blockIdx.x, i0 = b*64, tid = threadIdx.x;  // 256 threads
  for (int k = tid; k < 512; k += 256)
    cb[k>>6][k&63] = colbitsP[(size_t)(k>>6)*4096 + i0 + (k&63)];
  if (tid < 64){ cs[tid] = cst[i0+tid].w; ss[tid] = s0[i0+tid]; }
  __syncthreads();
  float rho = hdr[0];
  float r2t = 512.0f*rho*rho;
  #pragma unroll
  for (int k = 0; k < 16; ++k){
    int q = tid*16 + k;
    int t = q >> 6, j = q & 63;
    int acc = 0;
    #pragma unroll
    for (int wl = 0; wl < 8; ++wl) acc += __popcll(cb[wl][t] ^ cb[wl][j]);
    float G = (float)(512 - 2*acc);
    float kf = G - rho*(cs[t]+cs[j]) + r2t;
    Kl[t][j] = kf;
    Kf[(size_t)b*4096 + q] = kf;
  }
  __syncthreads();
  if (tid < 64){
    float bc = 0.0f;
    for (int j = 0; j < tid; ++j) bc = fmaf(ss[j], Kl[tid][j], bc);
    baseCorr[i0 + tid] = bc;
  }
  if (tid == 64){
    float a = 0.0f, b2 = 0.0f;
    for (int j = 0; j < 64; ++j){ a += ss[j]; b2 = fmaf(ss[j], cs[j], b2); }
    blkS0[b] = a; blkS0C[b] = b2;
  }
}

// ---- U[b][l]
__global__ void k_u(const unsigned long long* __restrict__ xbits, const float* __restrict__ s0,
                    float* __restrict__ U){
  __shared__ float s0l[64];
  int b = blockIdx.x, l = threadIdx.x;  // 512 threads
  if (l < 64) s0l[l] = s0[b*64 + l];
  __syncthreads();
  unsigned long long w = xbits[(size_t)l*64 + b];
  unsigned int lo = (unsigned)w, hi = (unsigned)(w >> 32);
  unsigned int nlo = ~lo, nhi = ~hi;
  float acc = 0.0f;
  #pragma unroll
  for (int j = 0; j < 32; ++j){
    unsigned int m = (nlo << (31-j)) & 0x80000000u;
    acc += __uint_as_float(__float_as_uint(s0l[j]) ^ m);
  }
  #pragma unroll
  for (int j = 0; j < 32; ++j){
    unsigned int m = (nhi << (31-j)) & 0x80000000u;
    acc += __uint_as_float(__float_as_uint(s0l[32+j]) ^ m);
  }
  U[(size_t)b*512 + l] = acc;
}

// ---- p0
__global__ void k_pinit(const float* __restrict__ llv, const float* __restrict__ s0,
                        float* __restrict__ p0){
  int l = blockIdx.x, lane = threadIdx.x;
  float acc = 0.0f;
  for (int c = 0; c < 64; ++c){
    float v = llv[(size_t)l*4096 + c*64 + lane];
    float sg = (v >= 0.0f) ? 1.0f : -1.0f;
    acc = fmaf(sg, s0[c*64 + lane], acc);
  }
  float tot = wave_allsum(acc);
  if (lane == 0) p0[l] = tot;
}

// ---- phase-1: accumulate into named accumulator (r15-proven 4-acc form)
#define ACCX(A, F, W, JS) { \
  unsigned int m_ = ((~(W)) << (31-(JS))) & 0x80000000u; \
  A += __uint_as_float(__float_as_uint(F) ^ m_); }
#define ACCQ(A, F, W, JS) { float4 q_ = pw[F]; \
  ACCX(A, q_.x, W, (JS)+0) ACCX(A, q_.y, W, (JS)+1) \
  ACCX(A, q_.z, W, (JS)+2) ACCX(A, q_.w, W, (JS)+3) }

// ---- ballot chain step (r14 verbatim — best measured)
#define BSTP(KVAL, J) { \
  unsigned long long neg_ = __ballot(__float_as_int(v) < 0); \
  unsigned b_ = (unsigned)(neg_ >> (J)) & 1u; \
  sg_ |= ((unsigned long long)(b_ ^ 1u)) << (J); \
  v = v + __uint_as_float(__float_as_uint(KVAL) ^ (b_ << 31)); }
#define BST4(Q, J0) BSTP(Q.x,(J0)+0) BSTP(Q.y,(J0)+1) BSTP(Q.z,(J0)+2) BSTP(Q.w,(J0)+3)

// ---- the sweep: LDS-resident + T14 async-stage + redundant all-wave chain
__global__ __launch_bounds__(512, 1)
void k_sweep6(const unsigned long long* __restrict__ colbitsP,
              const unsigned long long* __restrict__ xbitsW,
              const float* __restrict__ Kf, const float* __restrict__ baseCorr,
              const float* __restrict__ blkS0, const float* __restrict__ blkS0C,
              const float* __restrict__ U, const float4* __restrict__ cst,
              const float* __restrict__ p0, const float* __restrict__ s0,
              const float* __restrict__ hdr, unsigned long long* __restrict__ sbits)
{
  __shared__ float Kl[2][64][64];                 // 32 KB, f4-swizzled rows
  __shared__ unsigned long long cbl[2][8][64];    // 8 KB
  __shared__ unsigned long long xbl[2][512];      // 8 KB
  __shared__ float Ul[2][512];                    // 4 KB
  __shared__ float4 cstl[2][64];                  // 2 KB
  __shared__ float bcl[2][64];                    // 0.5 KB
  __shared__ float bs0l[64], bscl[64];            // 0.5 KB
  __shared__ float p[512];
  __shared__ float part[2][8][64];                // 4 KB, parity double-buffer
  __shared__ float red[512];

  int tid = threadIdx.x, g = tid >> 6, t = tid & 63;
  float rho = hdr[0];

  // prologue: p, P, T + per-block scalars
  p[tid] = p0[tid];
  red[tid] = p0[tid];
  if (tid < 64){ bs0l[tid] = blkS0[tid]; bscl[tid] = blkS0C[tid]; }
  __syncthreads();
  for (int st = 256; st > 0; st >>= 1){ if (tid < st) red[tid] += red[tid+st]; __syncthreads(); }
  float Preg = red[0];
  __syncthreads();
  { float a = 0.0f; for (int k = 0; k < 8; ++k) a += s0[tid*8 + k]; red[tid] = a; }
  __syncthreads();
  for (int st = 256; st > 0; st >>= 1){ if (tid < st) red[tid] += red[tid+st]; __syncthreads(); }
  float Treg = red[0];
  __syncthreads();

  // ---- stage group 0 directly ----
  {
    const float4* Ks = (const float4*)(Kf);
    #pragma unroll
    for (int k = 0; k < 4; ++k){
      int e = tid + k*512;
      float4 vv = Ks[e];
      int gie = e >> 10, row = (e >> 4) & 63, f = e & 15;
      *((float4*)&Kl[gie][row][0] + (f ^ (row & 15))) = vv;
    }
    #pragma unroll
    for (int k = 0; k < 2; ++k){
      int e = tid + k*512;
      int run = e >> 6, tt = e & 63, gie = run >> 3, wl = run & 7;
      cbl[gie][wl][tt] = colbitsP[(size_t)wl*4096 + gie*64 + tt];
    }
    #pragma unroll
    for (int k = 0; k < 2; ++k){
      int e = tid + k*512;
      ((unsigned long long*)xbl)[e] = xbitsW[e];
    }
    #pragma unroll
    for (int k = 0; k < 2; ++k){
      int e = tid + k*512;
      ((float*)Ul)[e] = U[e];
    }
    if (tid < 128){
      ((float4*)cstl)[tid] = cst[tid];
      ((float*)bcl)[tid]   = baseCorr[tid];
    }
  }
  __syncthreads();

  for (int grp = 0; grp < 32; ++grp){
    int ng = grp + 1;
    bool pf = (ng < 32);
    // ---- T14 issue-early: next group's loads into registers ----
    float4 kv0, kv1, kv2, kv3, cstv;
    unsigned long long cbv0, cbv1, xbv0, xbv1;
    float uv0, uv1, bcv;
    if (pf){
      const float4* Ks = (const float4*)(Kf + (size_t)ng*8192);
      kv0 = Ks[tid]; kv1 = Ks[tid+512]; kv2 = Ks[tid+1024]; kv3 = Ks[tid+1536];
      { int e = tid;       int run = e>>6, tt = e&63;
        cbv0 = colbitsP[(size_t)(run&7)*4096 + (ng*2 + (run>>3))*64 + tt]; }
      { int e = tid + 512; int run = e>>6, tt = e&63;
        cbv1 = colbitsP[(size_t)(run&7)*4096 + (ng*2 + (run>>3))*64 + tt]; }
      xbv0 = xbitsW[(size_t)ng*1024 + tid]; xbv1 = xbitsW[(size_t)ng*1024 + tid + 512];
      uv0  = U[(size_t)ng*1024 + tid];      uv1  = U[(size_t)ng*1024 + tid + 512];
      if (tid < 128){ cstv = cst[ng*128 + tid]; bcv = baseCorr[ng*128 + tid]; }
    }

    #pragma unroll
    for (int gi = 0; gi < 2; ++gi){
      int b = grp*2 + gi;
      // ---- phase 1 (4 accumulators, r15-proven) ----
      {
        unsigned long long w = cbl[gi][g][t];
        unsigned int lo = (unsigned)w, hi = (unsigned)(w >> 32);
        const float4* pw = (const float4*)(p + g*64);
        float a0 = 0.0f, a1 = 0.0f, a2 = 0.0f, a3 = 0.0f;
        ACCQ(a0, 0,  lo, 0)  ACCQ(a0, 1,  lo, 4)  ACCQ(a0, 2,  lo, 8)  ACCQ(a0, 3,  lo, 12)
        ACCQ(a1, 4,  lo, 16) ACCQ(a1, 5,  lo, 20) ACCQ(a1, 6,  lo, 24) ACCQ(a1, 7,  lo, 28)
        ACCQ(a2, 8,  hi, 0)  ACCQ(a2, 9,  hi, 4)  ACCQ(a2, 10, hi, 8)  ACCQ(a2, 11, hi, 12)
        ACCQ(a3, 12, hi, 16) ACCQ(a3, 13, hi, 20) ACCQ(a3, 14, hi, 24) ACCQ(a3, 15, hi, 28)
        part[gi][g][t] = (a0 + a1) + (a2 + a3);
      }
      __syncthreads();                             // B1 (only barrier per block)

      // ---- chain: ALL waves compute identical sg_ (no B2, no sig) ----
      unsigned long long sg_ = 0ull;
      {
        const float4* Kp = (const float4*)&Kl[gi][t][0];
        int sw = t & 15;
        float S = 0.0f;
        #pragma unroll
        for (int gg = 0; gg < 8; ++gg) S += part[gi][gg][t];
        float4 cc = cstl[gi][t];
        float bc_ = bcl[gi][t];
        float v = S - cc.x - rho*Preg - cc.y*Treg - bc_;
        float4 C0 = Kp[0^sw], C1 = Kp[1^sw], C2 = Kp[2^sw];
        BST4(C0, 0);   C0 = Kp[3^sw];
        BST4(C1, 4);   C1 = Kp[4^sw];
        BST4(C2, 8);   C2 = Kp[5^sw];
        BST4(C0, 12);  C0 = Kp[6^sw];
        BST4(C1, 16);  C1 = Kp[7^sw];
        BST4(C2, 20);  C2 = Kp[8^sw];
        BST4(C0, 24);  C0 = Kp[9^sw];
        BST4(C1, 28);  C1 = Kp[10^sw];
        BST4(C2, 32);  C2 = Kp[11^sw];
        BST4(C0, 36);  C0 = Kp[12^sw];
        BST4(C1, 40);  C1 = Kp[13^sw];
        BST4(C2, 44);  C2 = Kp[14^sw];
        BST4(C0, 48);  C0 = Kp[15^sw];
        BST4(C1, 52);
        BST4(C2, 56);
        BST4(C0, 60);
        if (tid == 0) sbits[b] = sg_;
        // P/T update (redundant per wave, identical values)
        float sv = ((sg_ >> t) & 1ull) ? cc.w : -cc.w;
        float sc = wave_allsum(sv);
        int pcs = __popcll(sg_);
        Preg += sc - bscl[b];
        Treg += (float)(2*pcs - 64) - bs0l[b];
      }
      // ---- phase 3: p update with LOCAL sg_ (p wave-local; no barrier) ----
      {
        int pc = __popcll(xbl[gi][tid] ^ sg_);
        p[tid] = p[tid] + (float)(64 - 2*pc) - Ul[gi][tid];
      }
    }

    __syncthreads();                               // Bpre: all chains done
    // ---- T14 write-late: prefetched registers -> LDS ----
    if (pf){
      { int e = tid;        int gie=e>>10, row=(e>>4)&63, f=e&15;
        *((float4*)&Kl[gie][row][0] + (f ^ (row & 15))) = kv0; }
      { int e = tid + 512;  int gie=e>>10, row=(e>>4)&63, f=e&15;
        *((float4*)&Kl[gie][row][0] + (f ^ (row & 15))) = kv1; }
      { int e = tid + 1024; int gie=e>>10, row=(e>>4)&63, f=e&15;
        *((float4*)&Kl[gie][row][0] + (f ^ (row & 15))) = kv2; }
      { int e = tid + 1536; int gie=e>>10, row=(e>>4)&63, f=e&15;
        *((float4*)&Kl[gie][row][0] + (f ^ (row & 15))) = kv3; }
      { int e = tid;       int run=e>>6, tt=e&63; cbl[run>>3][run&7][tt] = cbv0; }
      { int e = tid + 512; int run=e>>6, tt=e&63; cbl[run>>3][run&7][tt] = cbv1; }
      ((unsigned long long*)xbl)[tid]       = xbv0;
      ((unsigned long long*)xbl)[tid + 512] = xbv1;
      ((float*)Ul)[tid]       = uv0;
      ((float*)Ul)[tid + 512] = uv1;
      if (tid < 128){ ((float4*)cstl)[tid] = cstv; ((float*)bcl)[tid] = bcv; }
    }
    __syncthreads();                               // B4 (group boundary)
  }
}

// ---- exact integer scores + argmax one-hot
__global__ void k_scores(const unsigned long long* __restrict__ xbits,
                         const unsigned long long* __restrict__ sbits,
                         float* __restrict__ out){
  __shared__ unsigned long long sb[64];
  __shared__ int bestkey;
  int tid = threadIdx.x;  // 512
  if (tid < 64) sb[tid] = sbits[tid];
  if (tid == 0) bestkey = -1;
  __syncthreads();
  int acc = 0;
  #pragma unroll
  for (int w = 0; w < 64; ++w)
    acc += __popcll(xbits[(size_t)tid*64 + w] ^ sb[w]);
  int dot = 4096 - 2*acc;
  int ad  = dot < 0 ? -dot : dot;
  int key = (ad << 10) | (511 - tid);
  atomicMax(&bestkey, key);
  __syncthreads();
  int bl = 511 - (bestkey & 1023);
  float val = (float)(bestkey >> 10) * (1.0f/4096.0f);
  out[tid] = (tid == bl) ? val : 0.0f;
}

extern "C" void kernel_launch(void* const* d_in, const int* in_sizes, int n_in,
                              void* d_out, int out_size, void* d_ws, size_t ws_size,
                              hipStream_t stream){
  const float* s0  = (const float*)d_in[0];   // [4096]
  const float* llv = (const float*)d_in[1];   // [512][4096]
  float* out = (float*)d_out;                 // [512]
  char* ws = (char*)d_ws;

  unsigned long long* colbitsP = (unsigned long long*)(ws + OFF_COLB);
  unsigned long long* xbits    = (unsigned long long*)(ws + OFF_XBITS);
  unsigned long long* xbitsW   = (unsigned long long*)(ws + OFF_XBW);
  float*  Kf    = (float*)(ws + OFF_KF);
  float*  bcorr = (float*)(ws + OFF_BCORR);
  float*  U     = (float*)(ws + OFF_U);
  float4* cst   = (float4*)(ws + OFF_CST);
  float*  p0    = (float*)(ws + OFF_P0);
  unsigned long long* sbits = (unsigned long long*)(ws + OFF_SBITS);
  int*    colcnt = (int*)(ws + OFF_CNT);
  float*  hdr   = (float*)(ws + OFF_HDR);
  float*  bS0   = (float*)(ws + OFF_BS0);
  float*  bS0C  = (float*)(ws + OFF_BS0C);

  k_xbits<<<128, 256, 0, stream>>>(llv, xbits, xbitsW);
  k_bitT<<<dim3(8, 64), 64, 0, stream>>>(xbits, colbitsP);
  k_colc<<<16, 256, 0, stream>>>(colbitsP, colcnt);
  k_rho<<<1, 256, 0, stream>>>(colcnt, hdr);
  k_const<<<16, 256, 0, stream>>>(colcnt, hdr, s0, cst);
  k_kdiag<<<64, 256, 0, stream>>>(colbitsP, cst, s0, hdr, Kf, bcorr, bS0, bS0C);
  k_u<<<64, 512, 0, stream>>>(xbits, s0, U);
  k_pinit<<<512, 64, 0, stream>>>(llv, s0, p0);
  k_sweep6<<<1, 512, 0, stream>>>(colbitsP, xbitsW, Kf, bcorr, bS0, bS0C, U, cst, p0, s0, hdr, sbits);
  k_scores<<<1, 512, 0, stream>>>(xbits, sbits, out);
}

// Round 19
// 210.540 us; speedup vs baseline: 1.1822x; 1.0562x over previous
//
#include <hip/hip_runtime.h>
#include <hip/hip_bf16.h>

// Hopfield forward, blocked factored Gauss-Seidel.
// Round 19 = r14 (best passing: 168.2us sweep) + ONE isolated change:
// phase-1 with 4 independent accumulators (code correctness-proven in r15/r18,
// both absmax 0). Everything else byte-identical to r14.

#define OFF_COLB   0u                       // u64 [8][4096]  colbitsP
#define OFF_XBITS  (256u<<10)               // u64 [512][64]  row bits
#define OFF_XBW    (512u<<10)               // u64 [64][512]  xbitsW
#define OFF_KF     (768u<<10)               // f32 [64][64][64] Kdiag : 1 MB
#define OFF_BCORR  (1792u<<10)              // f32 [4096] baseCorr
#define OFF_U      (1808u<<10)              // f32 [64][512] U
#define OFF_CST    (1936u<<10)              // float4 [4096]
#define OFF_P0     (2000u<<10)              // f32 [512]
#define OFF_SBITS  (2002u<<10)              // u64 [64]
#define OFF_CNT    (2003u<<10)              // int [4096]
#define OFF_HDR    (2019u<<10)              // f32 [16]
#define OFF_BS0    (2020u<<10)              // f32 [64]
#define OFF_BS0C   (2021u<<10)              // f32 [64]

template<int CTRL, int RMASK>
__device__ __forceinline__ float dpp_add(float x){
  int t = __builtin_amdgcn_update_dpp(0, __float_as_int(x), CTRL, RMASK, 0xf, true);
  return x + __int_as_float(t);
}
__device__ __forceinline__ float wave_allsum(float x){
  x = dpp_add<0x111,0xf>(x);
  x = dpp_add<0x112,0xf>(x);
  x = dpp_add<0x114,0xf>(x);
  x = dpp_add<0x118,0xf>(x);
  x = dpp_add<0x142,0xa>(x);
  x = dpp_add<0x143,0xc>(x);
  return __int_as_float(__builtin_amdgcn_readlane(__float_as_int(x), 63));
}

// ---- row bits + transposed-block layout
__global__ void k_xbits(const float* __restrict__ llv, unsigned long long* __restrict__ xbits,
                        unsigned long long* __restrict__ xbitsW){
  int w = threadIdx.x >> 6, lane = threadIdx.x & 63;
  int l = blockIdx.x*4 + w;
  unsigned long long myword = 0;
  for (int c = 0; c < 64; ++c){
    float v = llv[(size_t)l*4096 + c*64 + lane];
    unsigned long long b = __ballot(v >= 0.0f);
    if (c == lane) myword = b;
  }
  xbits[(size_t)l*64 + lane] = myword;
  xbitsW[(size_t)lane*512 + l] = myword;
}

// ---- bit transpose
__global__ void k_bitT(const unsigned long long* __restrict__ xbits,
                       unsigned long long* __restrict__ colbitsP){
  int li = blockIdx.x, ii = blockIdx.y, lane = threadIdx.x;
  unsigned long long w = xbits[(size_t)(li*64 + lane)*64 + ii];
  unsigned long long myw = 0;
  for (int j = 0; j < 64; ++j){
    unsigned long long b = __ballot((w >> j) & 1ull);
    if (j == lane) myw = b;
  }
  colbitsP[(size_t)li*4096 + ii*64 + lane] = myw;
}

// ---- column positive counts
__global__ void k_colc(const unsigned long long* __restrict__ colbitsP, int* __restrict__ colcnt){
  int i = blockIdx.x*256 + threadIdx.x;
  int c = 0;
  #pragma unroll
  for (int wl = 0; wl < 8; ++wl) c += __popcll(colbitsP[(size_t)wl*4096 + i]);
  colcnt[i] = c;
}

// ---- rho
__global__ void k_rho(const int* __restrict__ colcnt, float* __restrict__ hdr){
  __shared__ int sh[256];
  int tid = threadIdx.x;
  int s = 0;
  for (int k = tid; k < 4096; k += 256) s += colcnt[k];
  sh[tid] = s; __syncthreads();
  for (int st = 128; st > 0; st >>= 1){
    if (tid < st) sh[tid] += sh[tid + st];
    __syncthreads();
  }
  if (tid == 0){
    int num = 2*sh[0] - 2097152;
    hdr[0] = (float)num * (1.0f/2097152.0f);
  }
}

// ---- per-step constants
__global__ void k_const(const int* __restrict__ colcnt, const float* __restrict__ hdr,
                        const float* __restrict__ s0, float4* __restrict__ cst){
  int i = blockIdx.x*256 + threadIdx.x;
  float rho = hdr[0];
  float c  = (float)(2*colcnt[i] - 512);
  float r2 = rho*rho;
  float q  = 512.0f + 512.0f*r2 - 2.0f*rho*c;
  float s  = s0[i];
  float4 o;
  o.x = q * s;
  o.y = rho*c - 512.0f*r2;
  o.z = 1.0f - s;
  o.w = c;
  cst[i] = o;
}

// ---- diagonal K blocks + baseCorr + block s0 sums
__global__ void k_kdiag(const unsigned long long* __restrict__ colbitsP,
                        const float4* __restrict__ cst, const float* __restrict__ s0,
                        const float* __restrict__ hdr,
                        float* __restrict__ Kf, float* __restrict__ baseCorr,
                        float* __restrict__ blkS0, float* __restrict__ blkS0C){
  __shared__ unsigned long long cb[8][64];
  __shared__ float Kl[64][64];
  __shared__ float cs[64], ss[64];
  int b = blockIdx.x, i0 = b*64, tid = threadIdx.x;  // 256 threads
  for (int k = tid; k < 512; k += 256)
    cb[k>>6][k&63] = colbitsP[(size_t)(k>>6)*4096 + i0 + (k&63)];
  if (tid < 64){ cs[tid] = cst[i0+tid].w; ss[tid] = s0[i0+tid]; }
  __syncthreads();
  float rho = hdr[0];
  float r2t = 512.0f*rho*rho;
  #pragma unroll
  for (int k = 0; k < 16; ++k){
    int q = tid*16 + k;
    int t = q >> 6, j = q & 63;
    int acc = 0;
    #pragma unroll
    for (int wl = 0; wl < 8; ++wl) acc += __popcll(cb[wl][t] ^ cb[wl][j]);
    float G = (float)(512 - 2*acc);
    float kf = G - rho*(cs[t]+cs[j]) + r2t;
    Kl[t][j] = kf;
    Kf[(size_t)b*4096 + q] = kf;
  }
  __syncthreads();
  if (tid < 64){
    float bc = 0.0f;
    for (int j = 0; j < tid; ++j) bc = fmaf(ss[j], Kl[tid][j], bc);
    baseCorr[i0 + tid] = bc;
  }
  if (tid == 64){
    float a = 0.0f, b2 = 0.0f;
    for (int j = 0; j < 64; ++j){ a += ss[j]; b2 = fmaf(ss[j], cs[j], b2); }
    blkS0[b] = a; blkS0C[b] = b2;
  }
}

// ---- U[b][l]
__global__ void k_u(const unsigned long long* __restrict__ xbits, const float* __restrict__ s0,
                    float* __restrict__ U){
  __shared__ float s0l[64];
  int b = blockIdx.x, l = threadIdx.x;  // 512 threads
  if (l < 64) s0l[l] = s0[b*64 + l];
  __syncthreads();
  unsigned long long w = xbits[(size_t)l*64 + b];
  unsigned int lo = (unsigned)w, hi = (unsigned)(w >> 32);
  unsigned int nlo = ~lo, nhi = ~hi;
  float acc = 0.0f;
  #pragma unroll
  for (int j = 0; j < 32; ++j){
    unsigned int m = (nlo << (31-j)) & 0x80000000u;
    acc += __uint_as_float(__float_as_uint(s0l[j]) ^ m);
  }
  #pragma unroll
  for (int j = 0; j < 32; ++j){
    unsigned int m = (nhi << (31-j)) & 0x80000000u;
    acc += __uint_as_float(__float_as_uint(s0l[32+j]) ^ m);
  }
  U[(size_t)b*512 + l] = acc;
}

// ---- p0
__global__ void k_pinit(const float* __restrict__ llv, const float* __restrict__ s0,
                        float* __restrict__ p0){
  int l = blockIdx.x, lane = threadIdx.x;
  float acc = 0.0f;
  for (int c = 0; c < 64; ++c){
    float v = llv[(size_t)l*4096 + c*64 + lane];
    float sg = (v >= 0.0f) ? 1.0f : -1.0f;
    acc = fmaf(sg, s0[c*64 + lane], acc);
  }
  float tot = wave_allsum(acc);
  if (lane == 0) p0[l] = tot;
}

// ---- phase-1: 4-accumulator form (r15/r18-proven)
#define ACCX(A, F, W, JS) { \
  unsigned int m_ = ((~(W)) << (31-(JS))) & 0x80000000u; \
  A += __uint_as_float(__float_as_uint(F) ^ m_); }
#define ACCQ(A, F, W, JS) { float4 q_ = pw[F]; \
  ACCX(A, q_.x, W, (JS)+0) ACCX(A, q_.y, W, (JS)+1) \
  ACCX(A, q_.z, W, (JS)+2) ACCX(A, q_.w, W, (JS)+3) }

// ---- ballot chain step (r14 verbatim — best measured)
#define BSTP(KVAL, J) { \
  unsigned long long neg_ = __ballot(__float_as_int(v) < 0); \
  unsigned b_ = (unsigned)(neg_ >> (J)) & 1u; \
  sg_ |= ((unsigned long long)(b_ ^ 1u)) << (J); \
  v = v + __uint_as_float(__float_as_uint(KVAL) ^ (b_ << 31)); }
#define BST4(Q, J0) BSTP(Q.x,(J0)+0) BSTP(Q.y,(J0)+1) BSTP(Q.z,(J0)+2) BSTP(Q.w,(J0)+3)

// ---- the sweep: LDS-resident + T14 async-stage + ballot chain (r14 structure)
__global__ __launch_bounds__(512, 1)
void k_sweep6(const unsigned long long* __restrict__ colbitsP,
              const unsigned long long* __restrict__ xbitsW,
              const float* __restrict__ Kf, const float* __restrict__ baseCorr,
              const float* __restrict__ blkS0, const float* __restrict__ blkS0C,
              const float* __restrict__ U, const float4* __restrict__ cst,
              const float* __restrict__ p0, const float* __restrict__ s0,
              const float* __restrict__ hdr, unsigned long long* __restrict__ sbits)
{
  __shared__ float Kl[2][64][64];                 // 32 KB, f4-swizzled rows
  __shared__ unsigned long long cbl[2][8][64];    // 8 KB
  __shared__ unsigned long long xbl[2][512];      // 8 KB
  __shared__ float Ul[2][512];                    // 4 KB
  __shared__ float4 cstl[2][64];                  // 2 KB
  __shared__ float bcl[2][64];                    // 0.5 KB
  __shared__ float bs0l[64], bscl[64];            // 0.5 KB
  __shared__ float p[512];
  __shared__ float part[8][64];
  __shared__ float red[512];
  __shared__ unsigned long long sig;

  int tid = threadIdx.x, g = tid >> 6, t = tid & 63;
  float rho = hdr[0];

  // prologue: p, P, T + per-block scalars
  p[tid] = p0[tid];
  red[tid] = p0[tid];
  if (tid < 64){ bs0l[tid] = blkS0[tid]; bscl[tid] = blkS0C[tid]; }
  __syncthreads();
  for (int st = 256; st > 0; st >>= 1){ if (tid < st) red[tid] += red[tid+st]; __syncthreads(); }
  float Preg = red[0];
  __syncthreads();
  { float a = 0.0f; for (int k = 0; k < 8; ++k) a += s0[tid*8 + k]; red[tid] = a; }
  __syncthreads();
  for (int st = 256; st > 0; st >>= 1){ if (tid < st) red[tid] += red[tid+st]; __syncthreads(); }
  float Treg = red[0];
  __syncthreads();

  // ---- stage group 0 directly ----
  {
    const float4* Ks = (const float4*)(Kf);
    #pragma unroll
    for (int k = 0; k < 4; ++k){
      int e = tid + k*512;
      float4 vv = Ks[e];
      int gie = e >> 10, row = (e >> 4) & 63, f = e & 15;
      *((float4*)&Kl[gie][row][0] + (f ^ (row & 15))) = vv;
    }
    #pragma unroll
    for (int k = 0; k < 2; ++k){
      int e = tid + k*512;
      int run = e >> 6, tt = e & 63, gie = run >> 3, wl = run & 7;
      cbl[gie][wl][tt] = colbitsP[(size_t)wl*4096 + gie*64 + tt];
    }
    #pragma unroll
    for (int k = 0; k < 2; ++k){
      int e = tid + k*512;
      ((unsigned long long*)xbl)[e] = xbitsW[e];
    }
    #pragma unroll
    for (int k = 0; k < 2; ++k){
      int e = tid + k*512;
      ((float*)Ul)[e] = U[e];
    }
    if (tid < 128){
      ((float4*)cstl)[tid] = cst[tid];
      ((float*)bcl)[tid]   = baseCorr[tid];
    }
  }
  __syncthreads();

  for (int grp = 0; grp < 32; ++grp){
    int ng = grp + 1;
    bool pf = (ng < 32);
    // ---- T14 issue-early: next group's loads into registers ----
    float4 kv0, kv1, kv2, kv3, cstv;
    unsigned long long cbv0, cbv1, xbv0, xbv1;
    float uv0, uv1, bcv;
    if (pf){
      const float4* Ks = (const float4*)(Kf + (size_t)ng*8192);
      kv0 = Ks[tid]; kv1 = Ks[tid+512]; kv2 = Ks[tid+1024]; kv3 = Ks[tid+1536];
      { int e = tid;       int run = e>>6, tt = e&63;
        cbv0 = colbitsP[(size_t)(run&7)*4096 + (ng*2 + (run>>3))*64 + tt]; }
      { int e = tid + 512; int run = e>>6, tt = e&63;
        cbv1 = colbitsP[(size_t)(run&7)*4096 + (ng*2 + (run>>3))*64 + tt]; }
      xbv0 = xbitsW[(size_t)ng*1024 + tid]; xbv1 = xbitsW[(size_t)ng*1024 + tid + 512];
      uv0  = U[(size_t)ng*1024 + tid];      uv1  = U[(size_t)ng*1024 + tid + 512];
      if (tid < 128){ cstv = cst[ng*128 + tid]; bcv = baseCorr[ng*128 + tid]; }
    }

    #pragma unroll
    for (int gi = 0; gi < 2; ++gi){
      int b = grp*2 + gi;
      // ---- phase 1: 4 accumulators (the only change vs r14) ----
      {
        unsigned long long w = cbl[gi][g][t];
        unsigned int lo = (unsigned)w, hi = (unsigned)(w >> 32);
        const float4* pw = (const float4*)(p + g*64);
        float a0 = 0.0f, a1 = 0.0f, a2 = 0.0f, a3 = 0.0f;
        ACCQ(a0, 0,  lo, 0)  ACCQ(a0, 1,  lo, 4)  ACCQ(a0, 2,  lo, 8)  ACCQ(a0, 3,  lo, 12)
        ACCQ(a1, 4,  lo, 16) ACCQ(a1, 5,  lo, 20) ACCQ(a1, 6,  lo, 24) ACCQ(a1, 7,  lo, 28)
        ACCQ(a2, 8,  hi, 0)  ACCQ(a2, 9,  hi, 4)  ACCQ(a2, 10, hi, 8)  ACCQ(a2, 11, hi, 12)
        ACCQ(a3, 12, hi, 16) ACCQ(a3, 13, hi, 20) ACCQ(a3, 14, hi, 24) ACCQ(a3, 15, hi, 28)
        part[g][t] = (a0 + a1) + (a2 + a3);
      }
      __syncthreads();                             // B1

      if (g == 0){
        const float4* Kp = (const float4*)&Kl[gi][t][0];
        int sw = t & 15;
        float S = 0.0f;
        #pragma unroll
        for (int gg = 0; gg < 8; ++gg) S += part[gg][t];
        float4 cc = cstl[gi][t];
        float bc_ = bcl[gi][t];
        float v = S - cc.x - rho*Preg - cc.y*Treg - bc_;
        float4 C0 = Kp[0^sw], C1 = Kp[1^sw], C2 = Kp[2^sw];
        unsigned long long sg_ = 0ull;
        BST4(C0, 0);   C0 = Kp[3^sw];
        BST4(C1, 4);   C1 = Kp[4^sw];
        BST4(C2, 8);   C2 = Kp[5^sw];
        BST4(C0, 12);  C0 = Kp[6^sw];
        BST4(C1, 16);  C1 = Kp[7^sw];
        BST4(C2, 20);  C2 = Kp[8^sw];
        BST4(C0, 24);  C0 = Kp[9^sw];
        BST4(C1, 28);  C1 = Kp[10^sw];
        BST4(C2, 32);  C2 = Kp[11^sw];
        BST4(C0, 36);  C0 = Kp[12^sw];
        BST4(C1, 40);  C1 = Kp[13^sw];
        BST4(C2, 44);  C2 = Kp[14^sw];
        BST4(C0, 48);  C0 = Kp[15^sw];
        BST4(C1, 52);
        BST4(C2, 56);
        BST4(C0, 60);
        if (t == 0){ sig = sg_; sbits[b] = sg_; }
        float sv = ((sg_ >> t) & 1ull) ? cc.w : -cc.w;
        float sc = wave_allsum(sv);
        int pcs = __popcll(sg_);
        Preg += sc - bscl[b];
        Treg += (float)(2*pcs - 64) - bs0l[b];
      }
      __syncthreads();                             // B2
      // ---- phase 3 (no B3: p wave-local; part/sig guarded by B1/B2) ----
      {
        unsigned long long sgv = sig;
        int pc = __popcll(xbl[gi][tid] ^ sgv);
        p[tid] = p[tid] + (float)(64 - 2*pc) - Ul[gi][tid];
      }
    }

    // ---- T14 write-late: prefetched registers -> LDS, then group barrier ----
    if (pf){
      { int e = tid;        int gie=e>>10, row=(e>>4)&63, f=e&15;
        *((float4*)&Kl[gie][row][0] + (f ^ (row & 15))) = kv0; }
      { int e = tid + 512;  int gie=e>>10, row=(e>>4)&63, f=e&15;
        *((float4*)&Kl[gie][row][0] + (f ^ (row & 15))) = kv1; }
      { int e = tid + 1024; int gie=e>>10, row=(e>>4)&63, f=e&15;
        *((float4*)&Kl[gie][row][0] + (f ^ (row & 15))) = kv2; }
      { int e = tid + 1536; int gie=e>>10, row=(e>>4)&63, f=e&15;
        *((float4*)&Kl[gie][row][0] + (f ^ (row & 15))) = kv3; }
      { int e = tid;       int run=e>>6, tt=e&63; cbl[run>>3][run&7][tt] = cbv0; }
      { int e = tid + 512; int run=e>>6, tt=e&63; cbl[run>>3][run&7][tt] = cbv1; }
      ((unsigned long long*)xbl)[tid]       = xbv0;
      ((unsigned long long*)xbl)[tid + 512] = xbv1;
      ((float*)Ul)[tid]       = uv0;
      ((float*)Ul)[tid + 512] = uv1;
      if (tid < 128){ ((float4*)cstl)[tid] = cstv; ((float*)bcl)[tid] = bcv; }
    }
    __syncthreads();                               // B4 (group boundary)
  }
}

// ---- exact integer scores + argmax one-hot
__global__ void k_scores(const unsigned long long* __restrict__ xbits,
                         const unsigned long long* __restrict__ sbits,
                         float* __restrict__ out){
  __shared__ unsigned long long sb[64];
  __shared__ int bestkey;
  int tid = threadIdx.x;  // 512
  if (tid < 64) sb[tid] = sbits[tid];
  if (tid == 0) bestkey = -1;
  __syncthreads();
  int acc = 0;
  #pragma unroll
  for (int w = 0; w < 64; ++w)
    acc += __popcll(xbits[(size_t)tid*64 + w] ^ sb[w]);
  int dot = 4096 - 2*acc;
  int ad  = dot < 0 ? -dot : dot;
  int key = (ad << 10) | (511 - tid);
  atomicMax(&bestkey, key);
  __syncthreads();
  int bl = 511 - (bestkey & 1023);
  float val = (float)(bestkey >> 10) * (1.0f/4096.0f);
  out[tid] = (tid == bl) ? val : 0.0f;
}

extern "C" void kernel_launch(void* const* d_in, const int* in_sizes, int n_in,
                              void* d_out, int out_size, void* d_ws, size_t ws_size,
                              hipStream_t stream){
  const float* s0  = (const float*)d_in[0];   // [4096]
  const float* llv = (const float*)d_in[1];   // [512][4096]
  float* out = (float*)d_out;                 // [512]
  char* ws = (char*)d_ws;

  unsigned long long* colbitsP = (unsigned long long*)(ws + OFF_COLB);
  unsigned long long* xbits    = (unsigned long long*)(ws + OFF_XBITS);
  unsigned long long* xbitsW   = (unsigned long long*)(ws + OFF_XBW);
  float*  Kf    = (float*)(ws + OFF_KF);
  float*  bcorr = (float*)(ws + OFF_BCORR);
  float*  U     = (float*)(ws + OFF_U);
  float4* cst   = (float4*)(ws + OFF_CST);
  float*  p0    = (float*)(ws + OFF_P0);
  unsigned long long* sbits = (unsigned long long*)(ws + OFF_SBITS);
  int*    colcnt = (int*)(ws + OFF_CNT);
  float*  hdr   = (float*)(ws + OFF_HDR);
  float*  bS0   = (float*)(ws + OFF_BS0);
  float*  bS0C  = (float*)(ws + OFF_BS0C);

  k_xbits<<<128, 256, 0, stream>>>(llv, xbits, xbitsW);
  k_bitT<<<dim3(8, 64), 64, 0, stream>>>(xbits, colbitsP);
  k_colc<<<16, 256, 0, stream>>>(colbitsP, colcnt);
  k_rho<<<1, 256, 0, stream>>>(colcnt, hdr);
  k_const<<<16, 256, 0, stream>>>(colcnt, hdr, s0, cst);
  k_kdiag<<<64, 256, 0, stream>>>(colbitsP, cst, s0, hdr, Kf, bcorr, bS0, bS0C);
  k_u<<<64, 512, 0, stream>>>(xbits, s0, U);
  k_pinit<<<512, 64, 0, stream>>>(llv, s0, p0);
  k_sweep6<<<1, 512, 0, stream>>>(colbitsP, xbitsW, Kf, bcorr, bS0, bS0C, U, cst, p0, s0, hdr, sbits);
  k_scores<<<1, 512, 0, stream>>>(xbits, sbits, out);
}

// Round 20
// 205.242 us; speedup vs baseline: 1.2127x; 1.0258x over previous
//
#include <hip/hip_runtime.h>
#include <hip/hip_bf16.h>

// Hopfield forward, blocked factored Gauss-Seidel.
// Round 20 = r19 sweep UNCHANGED + pre-kernel fusion (launch-overhead harvest):
//  k_xbp  = k_xbits + k_pinit (one llv pass, bit-identical p0)
//  k_crc  = k_colc + k_rho + k_const (1 block x 1024, colcnt in LDS, exact ints)
//  k_kdu  = k_kdiag + k_u (64 x 512; Gram re-indexed tid*8 — exact popcounts)
// 9 -> 6 launches.

#define OFF_COLB   0u                       // u64 [8][4096]  colbitsP
#define OFF_XBITS  (256u<<10)               // u64 [512][64]  row bits
#define OFF_XBW    (512u<<10)               // u64 [64][512]  xbitsW
#define OFF_KF     (768u<<10)               // f32 [64][64][64] Kdiag : 1 MB
#define OFF_BCORR  (1792u<<10)              // f32 [4096] baseCorr
#define OFF_U      (1808u<<10)              // f32 [64][512] U
#define OFF_CST    (1936u<<10)              // float4 [4096]
#define OFF_P0     (2000u<<10)              // f32 [512]
#define OFF_SBITS  (2002u<<10)              // u64 [64]
#define OFF_HDR    (2019u<<10)              // f32 [16]
#define OFF_BS0    (2020u<<10)              // f32 [64]
#define OFF_BS0C   (2021u<<10)              // f32 [64]

template<int CTRL, int RMASK>
__device__ __forceinline__ float dpp_add(float x){
  int t = __builtin_amdgcn_update_dpp(0, __float_as_int(x), CTRL, RMASK, 0xf, true);
  return x + __int_as_float(t);
}
__device__ __forceinline__ float wave_allsum(float x){
  x = dpp_add<0x111,0xf>(x);
  x = dpp_add<0x112,0xf>(x);
  x = dpp_add<0x114,0xf>(x);
  x = dpp_add<0x118,0xf>(x);
  x = dpp_add<0x142,0xa>(x);
  x = dpp_add<0x143,0xc>(x);
  return __int_as_float(__builtin_amdgcn_readlane(__float_as_int(x), 63));
}

// ---- fused: row bits + transposed layout + p0 (one llv pass)
__global__ void k_xbp(const float* __restrict__ llv, const float* __restrict__ s0,
                      unsigned long long* __restrict__ xbits,
                      unsigned long long* __restrict__ xbitsW,
                      float* __restrict__ p0){
  int w = threadIdx.x >> 6, lane = threadIdx.x & 63;
  int l = blockIdx.x*4 + w;
  unsigned long long myword = 0;
  float acc = 0.0f;
  for (int c = 0; c < 64; ++c){
    float v = llv[(size_t)l*4096 + c*64 + lane];
    bool pos = (v >= 0.0f);
    unsigned long long b = __ballot(pos);
    if (c == lane) myword = b;
    float sg = pos ? 1.0f : -1.0f;
    acc = fmaf(sg, s0[c*64 + lane], acc);      // identical order to k_pinit
  }
  xbits[(size_t)l*64 + lane] = myword;
  xbitsW[(size_t)lane*512 + l] = myword;
  float tot = wave_allsum(acc);
  if (lane == 0) p0[l] = tot;
}

// ---- bit transpose (unchanged)
__global__ void k_bitT(const unsigned long long* __restrict__ xbits,
                       unsigned long long* __restrict__ colbitsP){
  int li = blockIdx.x, ii = blockIdx.y, lane = threadIdx.x;
  unsigned long long w = xbits[(size_t)(li*64 + lane)*64 + ii];
  unsigned long long myw = 0;
  for (int j = 0; j < 64; ++j){
    unsigned long long b = __ballot((w >> j) & 1ull);
    if (j == lane) myw = b;
  }
  colbitsP[(size_t)li*4096 + ii*64 + lane] = myw;
}

// ---- fused: colcnt + rho + per-step constants (1 block x 1024)
__global__ __launch_bounds__(1024, 1)
void k_crc(const unsigned long long* __restrict__ colbitsP,
           const float* __restrict__ s0,
           float* __restrict__ hdr, float4* __restrict__ cst){
  __shared__ int cc[4096];
  __shared__ int red[1024];
  __shared__ float rhosh;
  int tid = threadIdx.x;
  int part = 0;
  #pragma unroll
  for (int k = 0; k < 4; ++k){
    int i = tid*4 + k;
    int c = 0;
    #pragma unroll
    for (int wl = 0; wl < 8; ++wl) c += __popcll(colbitsP[(size_t)wl*4096 + i]);
    cc[i] = c;
    part += c;
  }
  red[tid] = part;
  __syncthreads();
  for (int st = 512; st > 0; st >>= 1){
    if (tid < st) red[tid] += red[tid + st];
    __syncthreads();
  }
  if (tid == 0){
    int num = 2*red[0] - 2097152;
    float r = (float)num * (1.0f/2097152.0f);
    hdr[0] = r; rhosh = r;
  }
  __syncthreads();
  float rho = rhosh;
  #pragma unroll
  for (int k = 0; k < 4; ++k){
    int i = tid*4 + k;
    float c  = (float)(2*cc[i] - 512);
    float r2 = rho*rho;
    float q  = 512.0f + 512.0f*r2 - 2.0f*rho*c;
    float s  = s0[i];
    float4 o;
    o.x = q * s;
    o.y = rho*c - 512.0f*r2;
    o.z = 1.0f - s;
    o.w = c;
    cst[i] = o;
  }
}

// ---- fused: diagonal K blocks + baseCorr + blkS0 + U (64 x 512)
__global__ __launch_bounds__(512, 1)
void k_kdu(const unsigned long long* __restrict__ colbitsP,
           const unsigned long long* __restrict__ xbits,
           const float4* __restrict__ cst, const float* __restrict__ s0,
           const float* __restrict__ hdr,
           float* __restrict__ Kf, float* __restrict__ baseCorr,
           float* __restrict__ blkS0, float* __restrict__ blkS0C,
           float* __restrict__ U){
  __shared__ unsigned long long cb[8][64];
  __shared__ float Kl[64][64];
  __shared__ float cs[64], ss[64];
  int b = blockIdx.x, i0 = b*64, tid = threadIdx.x;  // 512 threads
  if (tid < 512) cb[tid>>6][tid&63] = colbitsP[(size_t)(tid>>6)*4096 + i0 + (tid&63)];
  if (tid < 64){ cs[tid] = cst[i0+tid].w; ss[tid] = s0[i0+tid]; }
  __syncthreads();
  float rho = hdr[0];
  float r2t = 512.0f*rho*rho;
  #pragma unroll
  for (int k = 0; k < 8; ++k){
    int q = tid*8 + k;
    int t = q >> 6, j = q & 63;
    int acc = 0;
    #pragma unroll
    for (int wl = 0; wl < 8; ++wl) acc += __popcll(cb[wl][t] ^ cb[wl][j]);
    float G = (float)(512 - 2*acc);
    float kf = G - rho*(cs[t]+cs[j]) + r2t;
    Kl[t][j] = kf;
    Kf[(size_t)b*4096 + q] = kf;
  }
  // U phase (independent of Kl; ss ready since first barrier)
  {
    int l = tid;
    unsigned long long w = xbits[(size_t)l*64 + b];
    unsigned int lo = (unsigned)w, hi = (unsigned)(w >> 32);
    unsigned int nlo = ~lo, nhi = ~hi;
    float acc = 0.0f;
    #pragma unroll
    for (int j = 0; j < 32; ++j){
      unsigned int m = (nlo << (31-j)) & 0x80000000u;
      acc += __uint_as_float(__float_as_uint(ss[j]) ^ m);
    }
    #pragma unroll
    for (int j = 0; j < 32; ++j){
      unsigned int m = (nhi << (31-j)) & 0x80000000u;
      acc += __uint_as_float(__float_as_uint(ss[32+j]) ^ m);
    }
    U[(size_t)b*512 + l] = acc;
  }
  __syncthreads();
  if (tid < 64){
    float bc = 0.0f;
    for (int j = 0; j < tid; ++j) bc = fmaf(ss[j], Kl[tid][j], bc);
    baseCorr[i0 + tid] = bc;
  }
  if (tid == 64){
    float a = 0.0f, b2 = 0.0f;
    for (int j = 0; j < 64; ++j){ a += ss[j]; b2 = fmaf(ss[j], cs[j], b2); }
    blkS0[b] = a; blkS0C[b] = b2;
  }
}

// ---- phase-1: 4-accumulator form (r19)
#define ACCX(A, F, W, JS) { \
  unsigned int m_ = ((~(W)) << (31-(JS))) & 0x80000000u; \
  A += __uint_as_float(__float_as_uint(F) ^ m_); }
#define ACCQ(A, F, W, JS) { float4 q_ = pw[F]; \
  ACCX(A, q_.x, W, (JS)+0) ACCX(A, q_.y, W, (JS)+1) \
  ACCX(A, q_.z, W, (JS)+2) ACCX(A, q_.w, W, (JS)+3) }

// ---- ballot chain step (r14 — best measured)
#define BSTP(KVAL, J) { \
  unsigned long long neg_ = __ballot(__float_as_int(v) < 0); \
  unsigned b_ = (unsigned)(neg_ >> (J)) & 1u; \
  sg_ |= ((unsigned long long)(b_ ^ 1u)) << (J); \
  v = v + __uint_as_float(__float_as_uint(KVAL) ^ (b_ << 31)); }
#define BST4(Q, J0) BSTP(Q.x,(J0)+0) BSTP(Q.y,(J0)+1) BSTP(Q.z,(J0)+2) BSTP(Q.w,(J0)+3)

// ---- the sweep: r19 byte-identical
__global__ __launch_bounds__(512, 1)
void k_sweep6(const unsigned long long* __restrict__ colbitsP,
              const unsigned long long* __restrict__ xbitsW,
              const float* __restrict__ Kf, const float* __restrict__ baseCorr,
              const float* __restrict__ blkS0, const float* __restrict__ blkS0C,
              const float* __restrict__ U, const float4* __restrict__ cst,
              const float* __restrict__ p0, const float* __restrict__ s0,
              const float* __restrict__ hdr, unsigned long long* __restrict__ sbits)
{
  __shared__ float Kl[2][64][64];                 // 32 KB, f4-swizzled rows
  __shared__ unsigned long long cbl[2][8][64];    // 8 KB
  __shared__ unsigned long long xbl[2][512];      // 8 KB
  __shared__ float Ul[2][512];                    // 4 KB
  __shared__ float4 cstl[2][64];                  // 2 KB
  __shared__ float bcl[2][64];                    // 0.5 KB
  __shared__ float bs0l[64], bscl[64];            // 0.5 KB
  __shared__ float p[512];
  __shared__ float part[8][64];
  __shared__ float red[512];
  __shared__ unsigned long long sig;

  int tid = threadIdx.x, g = tid >> 6, t = tid & 63;
  float rho = hdr[0];

  p[tid] = p0[tid];
  red[tid] = p0[tid];
  if (tid < 64){ bs0l[tid] = blkS0[tid]; bscl[tid] = blkS0C[tid]; }
  __syncthreads();
  for (int st = 256; st > 0; st >>= 1){ if (tid < st) red[tid] += red[tid+st]; __syncthreads(); }
  float Preg = red[0];
  __syncthreads();
  { float a = 0.0f; for (int k = 0; k < 8; ++k) a += s0[tid*8 + k]; red[tid] = a; }
  __syncthreads();
  for (int st = 256; st > 0; st >>= 1){ if (tid < st) red[tid] += red[tid+st]; __syncthreads(); }
  float Treg = red[0];
  __syncthreads();

  {
    const float4* Ks = (const float4*)(Kf);
    #pragma unroll
    for (int k = 0; k < 4; ++k){
      int e = tid + k*512;
      float4 vv = Ks[e];
      int gie = e >> 10, row = (e >> 4) & 63, f = e & 15;
      *((float4*)&Kl[gie][row][0] + (f ^ (row & 15))) = vv;
    }
    #pragma unroll
    for (int k = 0; k < 2; ++k){
      int e = tid + k*512;
      int run = e >> 6, tt = e & 63, gie = run >> 3, wl = run & 7;
      cbl[gie][wl][tt] = colbitsP[(size_t)wl*4096 + gie*64 + tt];
    }
    #pragma unroll
    for (int k = 0; k < 2; ++k){
      int e = tid + k*512;
      ((unsigned long long*)xbl)[e] = xbitsW[e];
    }
    #pragma unroll
    for (int k = 0; k < 2; ++k){
      int e = tid + k*512;
      ((float*)Ul)[e] = U[e];
    }
    if (tid < 128){
      ((float4*)cstl)[tid] = cst[tid];
      ((float*)bcl)[tid]   = baseCorr[tid];
    }
  }
  __syncthreads();

  for (int grp = 0; grp < 32; ++grp){
    int ng = grp + 1;
    bool pf = (ng < 32);
    float4 kv0, kv1, kv2, kv3, cstv;
    unsigned long long cbv0, cbv1, xbv0, xbv1;
    float uv0, uv1, bcv;
    if (pf){
      const float4* Ks = (const float4*)(Kf + (size_t)ng*8192);
      kv0 = Ks[tid]; kv1 = Ks[tid+512]; kv2 = Ks[tid+1024]; kv3 = Ks[tid+1536];
      { int e = tid;       int run = e>>6, tt = e&63;
        cbv0 = colbitsP[(size_t)(run&7)*4096 + (ng*2 + (run>>3))*64 + tt]; }
      { int e = tid + 512; int run = e>>6, tt = e&63;
        cbv1 = colbitsP[(size_t)(run&7)*4096 + (ng*2 + (run>>3))*64 + tt]; }
      xbv0 = xbitsW[(size_t)ng*1024 + tid]; xbv1 = xbitsW[(size_t)ng*1024 + tid + 512];
      uv0  = U[(size_t)ng*1024 + tid];      uv1  = U[(size_t)ng*1024 + tid + 512];
      if (tid < 128){ cstv = cst[ng*128 + tid]; bcv = baseCorr[ng*128 + tid]; }
    }

    #pragma unroll
    for (int gi = 0; gi < 2; ++gi){
      int b = grp*2 + gi;
      {
        unsigned long long w = cbl[gi][g][t];
        unsigned int lo = (unsigned)w, hi = (unsigned)(w >> 32);
        const float4* pw = (const float4*)(p + g*64);
        float a0 = 0.0f, a1 = 0.0f, a2 = 0.0f, a3 = 0.0f;
        ACCQ(a0, 0,  lo, 0)  ACCQ(a0, 1,  lo, 4)  ACCQ(a0, 2,  lo, 8)  ACCQ(a0, 3,  lo, 12)
        ACCQ(a1, 4,  lo, 16) ACCQ(a1, 5,  lo, 20) ACCQ(a1, 6,  lo, 24) ACCQ(a1, 7,  lo, 28)
        ACCQ(a2, 8,  hi, 0)  ACCQ(a2, 9,  hi, 4)  ACCQ(a2, 10, hi, 8)  ACCQ(a2, 11, hi, 12)
        ACCQ(a3, 12, hi, 16) ACCQ(a3, 13, hi, 20) ACCQ(a3, 14, hi, 24) ACCQ(a3, 15, hi, 28)
        part[g][t] = (a0 + a1) + (a2 + a3);
      }
      __syncthreads();                             // B1

      if (g == 0){
        const float4* Kp = (const float4*)&Kl[gi][t][0];
        int sw = t & 15;
        float S = 0.0f;
        #pragma unroll
        for (int gg = 0; gg < 8; ++gg) S += part[gg][t];
        float4 cc = cstl[gi][t];
        float bc_ = bcl[gi][t];
        float v = S - cc.x - rho*Preg - cc.y*Treg - bc_;
        float4 C0 = Kp[0^sw], C1 = Kp[1^sw], C2 = Kp[2^sw];
        unsigned long long sg_ = 0ull;
        BST4(C0, 0);   C0 = Kp[3^sw];
        BST4(C1, 4);   C1 = Kp[4^sw];
        BST4(C2, 8);   C2 = Kp[5^sw];
        BST4(C0, 12);  C0 = Kp[6^sw];
        BST4(C1, 16);  C1 = Kp[7^sw];
        BST4(C2, 20);  C2 = Kp[8^sw];
        BST4(C0, 24);  C0 = Kp[9^sw];
        BST4(C1, 28);  C1 = Kp[10^sw];
        BST4(C2, 32);  C2 = Kp[11^sw];
        BST4(C0, 36);  C0 = Kp[12^sw];
        BST4(C1, 40);  C1 = Kp[13^sw];
        BST4(C2, 44);  C2 = Kp[14^sw];
        BST4(C0, 48);  C0 = Kp[15^sw];
        BST4(C1, 52);
        BST4(C2, 56);
        BST4(C0, 60);
        if (t == 0){ sig = sg_; sbits[b] = sg_; }
        float sv = ((sg_ >> t) & 1ull) ? cc.w : -cc.w;
        float sc = wave_allsum(sv);
        int pcs = __popcll(sg_);
        Preg += sc - bscl[b];
        Treg += (float)(2*pcs - 64) - bs0l[b];
      }
      __syncthreads();                             // B2
      {
        unsigned long long sgv = sig;
        int pc = __popcll(xbl[gi][tid] ^ sgv);
        p[tid] = p[tid] + (float)(64 - 2*pc) - Ul[gi][tid];
      }
    }

    if (pf){
      { int e = tid;        int gie=e>>10, row=(e>>4)&63, f=e&15;
        *((float4*)&Kl[gie][row][0] + (f ^ (row & 15))) = kv0; }
      { int e = tid + 512;  int gie=e>>10, row=(e>>4)&63, f=e&15;
        *((float4*)&Kl[gie][row][0] + (f ^ (row & 15))) = kv1; }
      { int e = tid + 1024; int gie=e>>10, row=(e>>4)&63, f=e&15;
        *((float4*)&Kl[gie][row][0] + (f ^ (row & 15))) = kv2; }
      { int e = tid + 1536; int gie=e>>10, row=(e>>4)&63, f=e&15;
        *((float4*)&Kl[gie][row][0] + (f ^ (row & 15))) = kv3; }
      { int e = tid;       int run=e>>6, tt=e&63; cbl[run>>3][run&7][tt] = cbv0; }
      { int e = tid + 512; int run=e>>6, tt=e&63; cbl[run>>3][run&7][tt] = cbv1; }
      ((unsigned long long*)xbl)[tid]       = xbv0;
      ((unsigned long long*)xbl)[tid + 512] = xbv1;
      ((float*)Ul)[tid]       = uv0;
      ((float*)Ul)[tid + 512] = uv1;
      if (tid < 128){ ((float4*)cstl)[tid] = cstv; ((float*)bcl)[tid] = bcv; }
    }
    __syncthreads();                               // B4 (group boundary)
  }
}

// ---- exact integer scores + argmax one-hot
__global__ void k_scores(const unsigned long long* __restrict__ xbits,
                         const unsigned long long* __restrict__ sbits,
                         float* __restrict__ out){
  __shared__ unsigned long long sb[64];
  __shared__ int bestkey;
  int tid = threadIdx.x;  // 512
  if (tid < 64) sb[tid] = sbits[tid];
  if (tid == 0) bestkey = -1;
  __syncthreads();
  int acc = 0;
  #pragma unroll
  for (int w = 0; w < 64; ++w)
    acc += __popcll(xbits[(size_t)tid*64 + w] ^ sb[w]);
  int dot = 4096 - 2*acc;
  int ad  = dot < 0 ? -dot : dot;
  int key = (ad << 10) | (511 - tid);
  atomicMax(&bestkey, key);
  __syncthreads();
  int bl = 511 - (bestkey & 1023);
  float val = (float)(bestkey >> 10) * (1.0f/4096.0f);
  out[tid] = (tid == bl) ? val : 0.0f;
}

extern "C" void kernel_launch(void* const* d_in, const int* in_sizes, int n_in,
                              void* d_out, int out_size, void* d_ws, size_t ws_size,
                              hipStream_t stream){
  const float* s0  = (const float*)d_in[0];   // [4096]
  const float* llv = (const float*)d_in[1];   // [512][4096]
  float* out = (float*)d_out;                 // [512]
  char* ws = (char*)d_ws;

  unsigned long long* colbitsP = (unsigned long long*)(ws + OFF_COLB);
  unsigned long long* xbits    = (unsigned long long*)(ws + OFF_XBITS);
  unsigned long long* xbitsW   = (unsigned long long*)(ws + OFF_XBW);
  float*  Kf    = (float*)(ws + OFF_KF);
  float*  bcorr = (float*)(ws + OFF_BCORR);
  float*  U     = (float*)(ws + OFF_U);
  float4* cst   = (float4*)(ws + OFF_CST);
  float*  p0    = (float*)(ws + OFF_P0);
  unsigned long long* sbits = (unsigned long long*)(ws + OFF_SBITS);
  float*  hdr   = (float*)(ws + OFF_HDR);
  float*  bS0   = (float*)(ws + OFF_BS0);
  float*  bS0C  = (float*)(ws + OFF_BS0C);

  k_xbp<<<128, 256, 0, stream>>>(llv, s0, xbits, xbitsW, p0);
  k_bitT<<<dim3(8, 64), 64, 0, stream>>>(xbits, colbitsP);
  k_crc<<<1, 1024, 0, stream>>>(colbitsP, s0, hdr, cst);
  k_kdu<<<64, 512, 0, stream>>>(colbitsP, xbits, cst, s0, hdr, Kf, bcorr, bS0, bS0C, U);
  k_sweep6<<<1, 512, 0, stream>>>(colbitsP, xbitsW, Kf, bcorr, bS0, bS0C, U, cst, p0, s0, hdr, sbits);
  k_scores<<<1, 512, 0, stream>>>(xbits, sbits, out);
}

// Round 21
// 202.405 us; speedup vs baseline: 1.2297x; 1.0140x over previous
//
#include <hip/hip_runtime.h>
#include <hip/hip_bf16.h>

// Hopfield forward, blocked factored Gauss-Seidel.
// Round 21 = r20 + (1) k_scores fused into sweep tail (sbits in LDS, exact
// integer argmax unchanged), (2) wave0 P/T epilogue moved after B2
// (r15-proven correctness; overlaps other waves' phase3/phase1).
// 6 -> 5 launches. Chain/staging byte-identical to r19/r20 best.

#define OFF_COLB   0u                       // u64 [8][4096]  colbitsP
#define OFF_XBITS  (256u<<10)               // u64 [512][64]  row bits
#define OFF_XBW    (512u<<10)               // u64 [64][512]  xbitsW
#define OFF_KF     (768u<<10)               // f32 [64][64][64] Kdiag : 1 MB
#define OFF_BCORR  (1792u<<10)              // f32 [4096] baseCorr
#define OFF_U      (1808u<<10)              // f32 [64][512] U
#define OFF_CST    (1936u<<10)              // float4 [4096]
#define OFF_P0     (2000u<<10)              // f32 [512]
#define OFF_HDR    (2019u<<10)              // f32 [16]
#define OFF_BS0    (2020u<<10)              // f32 [64]
#define OFF_BS0C   (2021u<<10)              // f32 [64]

template<int CTRL, int RMASK>
__device__ __forceinline__ float dpp_add(float x){
  int t = __builtin_amdgcn_update_dpp(0, __float_as_int(x), CTRL, RMASK, 0xf, true);
  return x + __int_as_float(t);
}
__device__ __forceinline__ float wave_allsum(float x){
  x = dpp_add<0x111,0xf>(x);
  x = dpp_add<0x112,0xf>(x);
  x = dpp_add<0x114,0xf>(x);
  x = dpp_add<0x118,0xf>(x);
  x = dpp_add<0x142,0xa>(x);
  x = dpp_add<0x143,0xc>(x);
  return __int_as_float(__builtin_amdgcn_readlane(__float_as_int(x), 63));
}

// ---- fused: row bits + transposed layout + p0 (one llv pass)
__global__ void k_xbp(const float* __restrict__ llv, const float* __restrict__ s0,
                      unsigned long long* __restrict__ xbits,
                      unsigned long long* __restrict__ xbitsW,
                      float* __restrict__ p0){
  int w = threadIdx.x >> 6, lane = threadIdx.x & 63;
  int l = blockIdx.x*4 + w;
  unsigned long long myword = 0;
  float acc = 0.0f;
  for (int c = 0; c < 64; ++c){
    float v = llv[(size_t)l*4096 + c*64 + lane];
    bool pos = (v >= 0.0f);
    unsigned long long b = __ballot(pos);
    if (c == lane) myword = b;
    float sg = pos ? 1.0f : -1.0f;
    acc = fmaf(sg, s0[c*64 + lane], acc);
  }
  xbits[(size_t)l*64 + lane] = myword;
  xbitsW[(size_t)lane*512 + l] = myword;
  float tot = wave_allsum(acc);
  if (lane == 0) p0[l] = tot;
}

// ---- bit transpose
__global__ void k_bitT(const unsigned long long* __restrict__ xbits,
                       unsigned long long* __restrict__ colbitsP){
  int li = blockIdx.x, ii = blockIdx.y, lane = threadIdx.x;
  unsigned long long w = xbits[(size_t)(li*64 + lane)*64 + ii];
  unsigned long long myw = 0;
  for (int j = 0; j < 64; ++j){
    unsigned long long b = __ballot((w >> j) & 1ull);
    if (j == lane) myw = b;
  }
  colbitsP[(size_t)li*4096 + ii*64 + lane] = myw;
}

// ---- fused: colcnt + rho + per-step constants (1 block x 1024)
__global__ __launch_bounds__(1024, 1)
void k_crc(const unsigned long long* __restrict__ colbitsP,
           const float* __restrict__ s0,
           float* __restrict__ hdr, float4* __restrict__ cst){
  __shared__ int cc[4096];
  __shared__ int red[1024];
  __shared__ float rhosh;
  int tid = threadIdx.x;
  int part = 0;
  #pragma unroll
  for (int k = 0; k < 4; ++k){
    int i = tid*4 + k;
    int c = 0;
    #pragma unroll
    for (int wl = 0; wl < 8; ++wl) c += __popcll(colbitsP[(size_t)wl*4096 + i]);
    cc[i] = c;
    part += c;
  }
  red[tid] = part;
  __syncthreads();
  for (int st = 512; st > 0; st >>= 1){
    if (tid < st) red[tid] += red[tid + st];
    __syncthreads();
  }
  if (tid == 0){
    int num = 2*red[0] - 2097152;
    float r = (float)num * (1.0f/2097152.0f);
    hdr[0] = r; rhosh = r;
  }
  __syncthreads();
  float rho = rhosh;
  #pragma unroll
  for (int k = 0; k < 4; ++k){
    int i = tid*4 + k;
    float c  = (float)(2*cc[i] - 512);
    float r2 = rho*rho;
    float q  = 512.0f + 512.0f*r2 - 2.0f*rho*c;
    float s  = s0[i];
    float4 o;
    o.x = q * s;
    o.y = rho*c - 512.0f*r2;
    o.z = 1.0f - s;
    o.w = c;
    cst[i] = o;
  }
}

// ---- fused: diagonal K blocks + baseCorr + blkS0 + U (64 x 512)
__global__ __launch_bounds__(512, 1)
void k_kdu(const unsigned long long* __restrict__ colbitsP,
           const unsigned long long* __restrict__ xbits,
           const float4* __restrict__ cst, const float* __restrict__ s0,
           const float* __restrict__ hdr,
           float* __restrict__ Kf, float* __restrict__ baseCorr,
           float* __restrict__ blkS0, float* __restrict__ blkS0C,
           float* __restrict__ U){
  __shared__ unsigned long long cb[8][64];
  __shared__ float Kl[64][64];
  __shared__ float cs[64], ss[64];
  int b = blockIdx.x, i0 = b*64, tid = threadIdx.x;  // 512 threads
  if (tid < 512) cb[tid>>6][tid&63] = colbitsP[(size_t)(tid>>6)*4096 + i0 + (tid&63)];
  if (tid < 64){ cs[tid] = cst[i0+tid].w; ss[tid] = s0[i0+tid]; }
  __syncthreads();
  float rho = hdr[0];
  float r2t = 512.0f*rho*rho;
  #pragma unroll
  for (int k = 0; k < 8; ++k){
    int q = tid*8 + k;
    int t = q >> 6, j = q & 63;
    int acc = 0;
    #pragma unroll
    for (int wl = 0; wl < 8; ++wl) acc += __popcll(cb[wl][t] ^ cb[wl][j]);
    float G = (float)(512 - 2*acc);
    float kf = G - rho*(cs[t]+cs[j]) + r2t;
    Kl[t][j] = kf;
    Kf[(size_t)b*4096 + q] = kf;
  }
  {
    int l = tid;
    unsigned long long w = xbits[(size_t)l*64 + b];
    unsigned int lo = (unsigned)w, hi = (unsigned)(w >> 32);
    unsigned int nlo = ~lo, nhi = ~hi;
    float acc = 0.0f;
    #pragma unroll
    for (int j = 0; j < 32; ++j){
      unsigned int m = (nlo << (31-j)) & 0x80000000u;
      acc += __uint_as_float(__float_as_uint(ss[j]) ^ m);
    }
    #pragma unroll
    for (int j = 0; j < 32; ++j){
      unsigned int m = (nhi << (31-j)) & 0x80000000u;
      acc += __uint_as_float(__float_as_uint(ss[32+j]) ^ m);
    }
    U[(size_t)b*512 + l] = acc;
  }
  __syncthreads();
  if (tid < 64){
    float bc = 0.0f;
    for (int j = 0; j < tid; ++j) bc = fmaf(ss[j], Kl[tid][j], bc);
    baseCorr[i0 + tid] = bc;
  }
  if (tid == 64){
    float a = 0.0f, b2 = 0.0f;
    for (int j = 0; j < 64; ++j){ a += ss[j]; b2 = fmaf(ss[j], cs[j], b2); }
    blkS0[b] = a; blkS0C[b] = b2;
  }
}

// ---- phase-1: 4-accumulator form
#define ACCX(A, F, W, JS) { \
  unsigned int m_ = ((~(W)) << (31-(JS))) & 0x80000000u; \
  A += __uint_as_float(__float_as_uint(F) ^ m_); }
#define ACCQ(A, F, W, JS) { float4 q_ = pw[F]; \
  ACCX(A, q_.x, W, (JS)+0) ACCX(A, q_.y, W, (JS)+1) \
  ACCX(A, q_.z, W, (JS)+2) ACCX(A, q_.w, W, (JS)+3) }

// ---- ballot chain step (r14 — best measured)
#define BSTP(KVAL, J) { \
  unsigned long long neg_ = __ballot(__float_as_int(v) < 0); \
  unsigned b_ = (unsigned)(neg_ >> (J)) & 1u; \
  sg_ |= ((unsigned long long)(b_ ^ 1u)) << (J); \
  v = v + __uint_as_float(__float_as_uint(KVAL) ^ (b_ << 31)); }
#define BST4(Q, J0) BSTP(Q.x,(J0)+0) BSTP(Q.y,(J0)+1) BSTP(Q.z,(J0)+2) BSTP(Q.w,(J0)+3)

// ---- the sweep + fused scores tail
__global__ __launch_bounds__(512, 1)
void k_sweep6(const unsigned long long* __restrict__ colbitsP,
              const unsigned long long* __restrict__ xbitsW,
              const unsigned long long* __restrict__ xbits,
              const float* __restrict__ Kf, const float* __restrict__ baseCorr,
              const float* __restrict__ blkS0, const float* __restrict__ blkS0C,
              const float* __restrict__ U, const float4* __restrict__ cst,
              const float* __restrict__ p0, const float* __restrict__ s0,
              const float* __restrict__ hdr, float* __restrict__ out)
{
  __shared__ float Kl[2][64][64];                 // 32 KB, f4-swizzled rows
  __shared__ unsigned long long cbl[2][8][64];    // 8 KB
  __shared__ unsigned long long xbl[2][512];      // 8 KB
  __shared__ float Ul[2][512];                    // 4 KB
  __shared__ float4 cstl[2][64];                  // 2 KB
  __shared__ float bcl[2][64];                    // 0.5 KB
  __shared__ float bs0l[64], bscl[64];            // 0.5 KB
  __shared__ float p[512];
  __shared__ float part[8][64];
  __shared__ float red[512];
  __shared__ unsigned long long sig;
  __shared__ unsigned long long sbl[64];          // sbits kept in LDS
  __shared__ int bestkey;

  int tid = threadIdx.x, g = tid >> 6, t = tid & 63;
  float rho = hdr[0];

  p[tid] = p0[tid];
  red[tid] = p0[tid];
  if (tid < 64){ bs0l[tid] = blkS0[tid]; bscl[tid] = blkS0C[tid]; }
  if (tid == 0) bestkey = -1;
  __syncthreads();
  for (int st = 256; st > 0; st >>= 1){ if (tid < st) red[tid] += red[tid+st]; __syncthreads(); }
  float Preg = red[0];
  __syncthreads();
  { float a = 0.0f; for (int k = 0; k < 8; ++k) a += s0[tid*8 + k]; red[tid] = a; }
  __syncthreads();
  for (int st = 256; st > 0; st >>= 1){ if (tid < st) red[tid] += red[tid+st]; __syncthreads(); }
  float Treg = red[0];
  __syncthreads();

  // ---- stage group 0 ----
  {
    const float4* Ks = (const float4*)(Kf);
    #pragma unroll
    for (int k = 0; k < 4; ++k){
      int e = tid + k*512;
      float4 vv = Ks[e];
      int gie = e >> 10, row = (e >> 4) & 63, f = e & 15;
      *((float4*)&Kl[gie][row][0] + (f ^ (row & 15))) = vv;
    }
    #pragma unroll
    for (int k = 0; k < 2; ++k){
      int e = tid + k*512;
      int run = e >> 6, tt = e & 63, gie = run >> 3, wl = run & 7;
      cbl[gie][wl][tt] = colbitsP[(size_t)wl*4096 + gie*64 + tt];
    }
    #pragma unroll
    for (int k = 0; k < 2; ++k){
      int e = tid + k*512;
      ((unsigned long long*)xbl)[e] = xbitsW[e];
    }
    #pragma unroll
    for (int k = 0; k < 2; ++k){
      int e = tid + k*512;
      ((float*)Ul)[e] = U[e];
    }
    if (tid < 128){
      ((float4*)cstl)[tid] = cst[tid];
      ((float*)bcl)[tid]   = baseCorr[tid];
    }
  }
  __syncthreads();

  for (int grp = 0; grp < 32; ++grp){
    int ng = grp + 1;
    bool pf = (ng < 32);
    float4 kv0, kv1, kv2, kv3, cstv;
    unsigned long long cbv0, cbv1, xbv0, xbv1;
    float uv0, uv1, bcv;
    if (pf){
      const float4* Ks = (const float4*)(Kf + (size_t)ng*8192);
      kv0 = Ks[tid]; kv1 = Ks[tid+512]; kv2 = Ks[tid+1024]; kv3 = Ks[tid+1536];
      { int e = tid;       int run = e>>6, tt = e&63;
        cbv0 = colbitsP[(size_t)(run&7)*4096 + (ng*2 + (run>>3))*64 + tt]; }
      { int e = tid + 512; int run = e>>6, tt = e&63;
        cbv1 = colbitsP[(size_t)(run&7)*4096 + (ng*2 + (run>>3))*64 + tt]; }
      xbv0 = xbitsW[(size_t)ng*1024 + tid]; xbv1 = xbitsW[(size_t)ng*1024 + tid + 512];
      uv0  = U[(size_t)ng*1024 + tid];      uv1  = U[(size_t)ng*1024 + tid + 512];
      if (tid < 128){ cstv = cst[ng*128 + tid]; bcv = baseCorr[ng*128 + tid]; }
    }

    #pragma unroll
    for (int gi = 0; gi < 2; ++gi){
      int b = grp*2 + gi;
      // ---- phase 1 (4 accumulators) ----
      {
        unsigned long long w = cbl[gi][g][t];
        unsigned int lo = (unsigned)w, hi = (unsigned)(w >> 32);
        const float4* pw = (const float4*)(p + g*64);
        float a0 = 0.0f, a1 = 0.0f, a2 = 0.0f, a3 = 0.0f;
        ACCQ(a0, 0,  lo, 0)  ACCQ(a0, 1,  lo, 4)  ACCQ(a0, 2,  lo, 8)  ACCQ(a0, 3,  lo, 12)
        ACCQ(a1, 4,  lo, 16) ACCQ(a1, 5,  lo, 20) ACCQ(a1, 6,  lo, 24) ACCQ(a1, 7,  lo, 28)
        ACCQ(a2, 8,  hi, 0)  ACCQ(a2, 9,  hi, 4)  ACCQ(a2, 10, hi, 8)  ACCQ(a2, 11, hi, 12)
        ACCQ(a3, 12, hi, 16) ACCQ(a3, 13, hi, 20) ACCQ(a3, 14, hi, 24) ACCQ(a3, 15, hi, 28)
        part[g][t] = (a0 + a1) + (a2 + a3);
      }
      __syncthreads();                             // B1

      unsigned long long sg_ = 0ull;
      float4 cc = make_float4(0.f,0.f,0.f,0.f);
      if (g == 0){
        const float4* Kp = (const float4*)&Kl[gi][t][0];
        int sw = t & 15;
        float S = 0.0f;
        #pragma unroll
        for (int gg = 0; gg < 8; ++gg) S += part[gg][t];
        cc = cstl[gi][t];
        float bc_ = bcl[gi][t];
        float v = S - cc.x - rho*Preg - cc.y*Treg - bc_;
        float4 C0 = Kp[0^sw], C1 = Kp[1^sw], C2 = Kp[2^sw];
        BST4(C0, 0);   C0 = Kp[3^sw];
        BST4(C1, 4);   C1 = Kp[4^sw];
        BST4(C2, 8);   C2 = Kp[5^sw];
        BST4(C0, 12);  C0 = Kp[6^sw];
        BST4(C1, 16);  C1 = Kp[7^sw];
        BST4(C2, 20);  C2 = Kp[8^sw];
        BST4(C0, 24);  C0 = Kp[9^sw];
        BST4(C1, 28);  C1 = Kp[10^sw];
        BST4(C2, 32);  C2 = Kp[11^sw];
        BST4(C0, 36);  C0 = Kp[12^sw];
        BST4(C1, 40);  C1 = Kp[13^sw];
        BST4(C2, 44);  C2 = Kp[14^sw];
        BST4(C0, 48);  C0 = Kp[15^sw];
        BST4(C1, 52);
        BST4(C2, 56);
        BST4(C0, 60);
        if (t == 0){ sig = sg_; sbl[b] = sg_; }
      }
      __syncthreads();                             // B2
      // ---- wave0 P/T epilogue AFTER B2 (overlaps other waves) ----
      if (g == 0){
        float sv = ((sg_ >> t) & 1ull) ? cc.w : -cc.w;
        float sc = wave_allsum(sv);
        int pcs = __popcll(sg_);
        Preg += sc - bscl[b];
        Treg += (float)(2*pcs - 64) - bs0l[b];
      }
      // ---- phase 3 ----
      {
        unsigned long long sgv = sig;
        int pc = __popcll(xbl[gi][tid] ^ sgv);
        p[tid] = p[tid] + (float)(64 - 2*pc) - Ul[gi][tid];
      }
    }

    __syncthreads();                               // Bpre (chains/phase3 done)
    if (pf){
      { int e = tid;        int gie=e>>10, row=(e>>4)&63, f=e&15;
        *((float4*)&Kl[gie][row][0] + (f ^ (row & 15))) = kv0; }
      { int e = tid + 512;  int gie=e>>10, row=(e>>4)&63, f=e&15;
        *((float4*)&Kl[gie][row][0] + (f ^ (row & 15))) = kv1; }
      { int e = tid + 1024; int gie=e>>10, row=(e>>4)&63, f=e&15;
        *((float4*)&Kl[gie][row][0] + (f ^ (row & 15))) = kv2; }
      { int e = tid + 1536; int gie=e>>10, row=(e>>4)&63, f=e&15;
        *((float4*)&Kl[gie][row][0] + (f ^ (row & 15))) = kv3; }
      { int e = tid;       int run=e>>6, tt=e&63; cbl[run>>3][run&7][tt] = cbv0; }
      { int e = tid + 512; int run=e>>6, tt=e&63; cbl[run>>3][run&7][tt] = cbv1; }
      ((unsigned long long*)xbl)[tid]       = xbv0;
      ((unsigned long long*)xbl)[tid + 512] = xbv1;
      ((float*)Ul)[tid]       = uv0;
      ((float*)Ul)[tid + 512] = uv1;
      if (tid < 128){ ((float4*)cstl)[tid] = cstv; ((float*)bcl)[tid] = bcv; }
    }
    __syncthreads();                               // B4 (group boundary)
  }

  // ---- fused scores tail: exact integer argmax one-hot (was k_scores) ----
  {
    int acc = 0;
    #pragma unroll
    for (int w = 0; w < 64; ++w)
      acc += __popcll(xbits[(size_t)tid*64 + w] ^ sbl[w]);
    int dot = 4096 - 2*acc;
    int ad  = dot < 0 ? -dot : dot;
    int key = (ad << 10) | (511 - tid);
    atomicMax(&bestkey, key);
    __syncthreads();
    int bl = 511 - (bestkey & 1023);
    float val = (float)(bestkey >> 10) * (1.0f/4096.0f);
    out[tid] = (tid == bl) ? val : 0.0f;
  }
}

extern "C" void kernel_launch(void* const* d_in, const int* in_sizes, int n_in,
                              void* d_out, int out_size, void* d_ws, size_t ws_size,
                              hipStream_t stream){
  const float* s0  = (const float*)d_in[0];   // [4096]
  const float* llv = (const float*)d_in[1];   // [512][4096]
  float* out = (float*)d_out;                 // [512]
  char* ws = (char*)d_ws;

  unsigned long long* colbitsP = (unsigned long long*)(ws + OFF_COLB);
  unsigned long long* xbits    = (unsigned long long*)(ws + OFF_XBITS);
  unsigned long long* xbitsW   = (unsigned long long*)(ws + OFF_XBW);
  float*  Kf    = (float*)(ws + OFF_KF);
  float*  bcorr = (float*)(ws + OFF_BCORR);
  float*  U     = (float*)(ws + OFF_U);
  float4* cst   = (float4*)(ws + OFF_CST);
  float*  p0    = (float*)(ws + OFF_P0);
  float*  hdr   = (float*)(ws + OFF_HDR);
  float*  bS0   = (float*)(ws + OFF_BS0);
  float*  bS0C  = (float*)(ws + OFF_BS0C);

  k_xbp<<<128, 256, 0, stream>>>(llv, s0, xbits, xbitsW, p0);
  k_bitT<<<dim3(8, 64), 64, 0, stream>>>(xbits, colbitsP);
  k_crc<<<1, 1024, 0, stream>>>(colbitsP, s0, hdr, cst);
  k_kdu<<<64, 512, 0, stream>>>(colbitsP, xbits, cst, s0, hdr, Kf, bcorr, bS0, bS0C, U);
  k_sweep6<<<1, 512, 0, stream>>>(colbitsP, xbitsW, xbits, Kf, bcorr, bS0, bS0C, U, cst, p0, s0, hdr, out);
}